// Round 4
// baseline (35780.075 us; speedup 1.0000x reference)
//
#include <hip/hip_runtime.h>
#include <cstddef>
#include <cstdint>

namespace {

constexpr int B = 256, S = 128, H = 512;
constexpr int NBLK = 256;   // persistent grid size (1 block per CU)
constexpr int NTHR = 512;   // 8 waves per CU
constexpr int GLS = 16;     // ints per gen-broadcast line (64B)

__device__ __forceinline__ float sigmf(float x) { return 1.f / (1.f + expf(-x)); }

// ---------------------------------------------------------------------------
// init: h <- h0, c <- c0, mask <- 1, barrier slots + gen lines <- 0
// ---------------------------------------------------------------------------
__global__ __launch_bounds__(512) void init_kernel(float* __restrict__ h,
                                                   float* __restrict__ c,
                                                   float* __restrict__ mask,
                                                   int* __restrict__ bar,
                                                   const float* __restrict__ h0,
                                                   const float* __restrict__ c0) {
  int tid = blockIdx.x * 512 + threadIdx.x;
  if (tid < B * H) {
    h[tid] = h0[tid];
    c[tid] = c0[tid];
  }
  if (tid < B * S) mask[tid] = 1.0f;
  if (tid < NBLK + NBLK * GLS) bar[tid] = 0;   // slots[256] + glines[256*16]
}

// ---------------------------------------------------------------------------
// Precompute GEMM: C = A @ Bw   (ctx_proj), fp32, row-major.
// ---------------------------------------------------------------------------
template <int BM, int BN, int TM, int TN, int KT>
__global__ __launch_bounds__((BM / TM) * (BN / TN)) void gemm_pre(
    const float* __restrict__ A, const float* __restrict__ Bw,
    float* __restrict__ C, int M, int N, int K) {
  constexpr int THREADS = (BM / TM) * (BN / TN);
  const int tid = threadIdx.x;
  const int n0 = blockIdx.x * BN;
  const int m0 = blockIdx.y * BM;

  __shared__ float As[KT][BM + 4];
  __shared__ float Bs[KT][BN];

  float acc[TM][TN];
#pragma unroll
  for (int i = 0; i < TM; ++i)
#pragma unroll
    for (int j = 0; j < TN; ++j) acc[i][j] = 0.f;

  const int tn = tid % (BN / TN);
  const int tm = tid / (BN / TN);

  for (int kk = 0; kk < K; kk += KT) {
    for (int idx = tid; idx < BM * (KT / 4); idx += THREADS) {
      int row = idx / (KT / 4), kq = idx % (KT / 4);
      float4 a4 = *reinterpret_cast<const float4*>(A + (size_t)(m0 + row) * K + kk + kq * 4);
      As[kq * 4 + 0][row] = a4.x;
      As[kq * 4 + 1][row] = a4.y;
      As[kq * 4 + 2][row] = a4.z;
      As[kq * 4 + 3][row] = a4.w;
    }
    for (int idx = tid; idx < KT * (BN / 4); idx += THREADS) {
      int k = idx / (BN / 4), n4 = idx % (BN / 4);
      *reinterpret_cast<float4*>(&Bs[k][n4 * 4]) =
          *reinterpret_cast<const float4*>(Bw + (size_t)(kk + k) * N + n0 + n4 * 4);
    }
    __syncthreads();
#pragma unroll
    for (int k = 0; k < KT; ++k) {
      float a[TM], bb[TN];
#pragma unroll
      for (int i = 0; i < TM; ++i) a[i] = As[k][tm * TM + i];
#pragma unroll
      for (int j = 0; j < TN; ++j) bb[j] = Bs[k][tn * TN + j];
#pragma unroll
      for (int i = 0; i < TM; ++i)
#pragma unroll
        for (int j = 0; j < TN; ++j) acc[i][j] = fmaf(a[i], bb[j], acc[i][j]);
    }
    __syncthreads();
  }
#pragma unroll
  for (int i = 0; i < TM; ++i)
#pragma unroll
    for (int j = 0; j < TN; ++j)
      C[(size_t)(m0 + tm * TM + i) * N + n0 + tn * TN + j] = acc[i][j];
}

// ---------------------------------------------------------------------------
// Broadcast-tree grid barrier — no cacheline is ever polled by >1 CU:
//   arrive : leader release-stores g into its OWN slot line
//   collect: block0 wave0 polls all 256 slots (4/lane)
//   fanout : block0 wave0 release-stores g into 256 per-block gen lines
//   depart : each leader spins on its OWN gen line
// ---------------------------------------------------------------------------
__device__ __forceinline__ void grid_barrier(int* __restrict__ slots,
                                             int* __restrict__ glines, int g) {
  __syncthreads();
  if (threadIdx.x == 0) {
    __threadfence();  // publish this block's writes before announcing arrival
    __hip_atomic_store(&slots[blockIdx.x], g, __ATOMIC_RELEASE,
                       __HIP_MEMORY_SCOPE_AGENT);
  }
  if (blockIdx.x == 0) {
    if (threadIdx.x < 64) {
      const int base = threadIdx.x * 4;
      for (;;) {
        int s0 = __hip_atomic_load(&slots[base + 0], __ATOMIC_ACQUIRE, __HIP_MEMORY_SCOPE_AGENT);
        int s1 = __hip_atomic_load(&slots[base + 1], __ATOMIC_ACQUIRE, __HIP_MEMORY_SCOPE_AGENT);
        int s2 = __hip_atomic_load(&slots[base + 2], __ATOMIC_ACQUIRE, __HIP_MEMORY_SCOPE_AGENT);
        int s3 = __hip_atomic_load(&slots[base + 3], __ATOMIC_ACQUIRE, __HIP_MEMORY_SCOPE_AGENT);
        bool ok = (s0 >= g) && (s1 >= g) && (s2 >= g) && (s3 >= g);
        if (__all(ok)) break;
        __builtin_amdgcn_s_sleep(1);
      }
    }
    __syncthreads();  // block-wide order: polls happened-before fanout
    if (threadIdx.x < 64) {
      __threadfence();
#pragma unroll
      for (int j = 0; j < 4; ++j)
        __hip_atomic_store(&glines[(threadIdx.x * 4 + j) * GLS], g,
                           __ATOMIC_RELEASE, __HIP_MEMORY_SCOPE_AGENT);
    }
    __syncthreads();
  } else {
    if (threadIdx.x == 0) {
      while (__hip_atomic_load(&glines[blockIdx.x * GLS], __ATOMIC_ACQUIRE,
                               __HIP_MEMORY_SCOPE_AGENT) < g)
        __builtin_amdgcn_s_sleep(1);
      __threadfence();  // discard stale cached lines before consuming
    }
    __syncthreads();
  }
}

// ---------------------------------------------------------------------------
// Persistent decoder: all 128 steps, 4 phases per step, grid barriers between.
// ---------------------------------------------------------------------------
__global__ __launch_bounds__(NTHR) void decoder_fused(
    const float* __restrict__ emb, const float* __restrict__ dec,
    const float* __restrict__ ctx, const float* __restrict__ Wi,
    const float* __restrict__ bi, const float* __restrict__ Wh,
    const float* __restrict__ bh, const float* __restrict__ Wha,
    const float* __restrict__ v, const float* __restrict__ Wout,
    const float* __restrict__ bout, const float* __restrict__ ctxp,
    float* __restrict__ gates, float* __restrict__ g_h,
    float* __restrict__ c0buf, float* __restrict__ c1buf,
    float* __restrict__ g_q, float* __restrict__ g_hp,
    float* __restrict__ g_att, float* __restrict__ g_msk,
    int* __restrict__ g_sel, int* __restrict__ barslots,
    int* __restrict__ barglines, float* __restrict__ out) {
  const int bid = blockIdx.x;
  const int tid = threadIdx.x;

  __shared__ union {
    struct { float As[64][33]; float Bs[64][64]; } p1;                 // 24.8 KB
    struct { float hi[16][512]; float Bs[64][68]; } p2;                // 49.8 KB
    struct { float es[128]; float attp[8][512]; float red[4]; int redi[2]; } p3; // ~17 KB
    struct { float As[64][33]; float Bs[64][20]; } p4;                 // 13.4 KB
  } sh;

  for (int t = 0; t < S; ++t) {
    const int gb = t * 4;
    const float* cr = (t & 1) ? c1buf : c0buf;
    float* cw = (t & 1) ? c0buf : c1buf;

    // ============ P1: gates = h@Wh + gather(x)@Wi + bi + bh ============
    {
      const int m0 = (bid >> 5) * 32;   // 8 m-tiles of 32 rows
      const int n0 = (bid & 31) * 64;   // 32 n-tiles of 64 cols (N=2048)
      const int tm = tid >> 4;          // 0..31 (1 row / thread)
      const int tn = tid & 15;          // 0..15 (4 cols / thread)
      float ac0 = 0.f, ac1 = 0.f, ac2 = 0.f, ac3 = 0.f;

      const int srow = tid >> 4;          // 0..31 (staging row)
      const int skq = (tid & 15) * 4;     // 0..60 (staging k quad)

      for (int part = 0; part < 2; ++part) {
        const float* Wp = part ? Wi : Wh;
        const float* ar;
        if (part == 0) {
          ar = g_h + (size_t)(m0 + srow) * H;
        } else if (t == 0) {
          ar = dec + (size_t)(m0 + srow) * H;
        } else {
          ar = emb + ((size_t)(m0 + srow) * S + g_sel[m0 + srow]) * H;
        }
        for (int kk = 0; kk < H; kk += 64) {
          float4 a4 = *reinterpret_cast<const float4*>(ar + kk + skq);
          sh.p1.As[skq + 0][srow] = a4.x;
          sh.p1.As[skq + 1][srow] = a4.y;
          sh.p1.As[skq + 2][srow] = a4.z;
          sh.p1.As[skq + 3][srow] = a4.w;
#pragma unroll
          for (int i = 0; i < 2; ++i) {
            int lin = tid + i * 512;
            int k = lin >> 4, c4 = (lin & 15) * 4;
            *reinterpret_cast<float4*>(&sh.p1.Bs[k][c4]) =
                *reinterpret_cast<const float4*>(Wp + (size_t)(kk + k) * 2048 + n0 + c4);
          }
          __syncthreads();
#pragma unroll 8
          for (int k = 0; k < 64; ++k) {
            float av = sh.p1.As[k][tm];
            float4 b4 = *reinterpret_cast<const float4*>(&sh.p1.Bs[k][tn * 4]);
            ac0 = fmaf(av, b4.x, ac0);
            ac1 = fmaf(av, b4.y, ac1);
            ac2 = fmaf(av, b4.z, ac2);
            ac3 = fmaf(av, b4.w, ac3);
          }
          __syncthreads();
        }
      }
      const int cA = n0 + tn * 4;
      float4 o;
      o.x = ac0 + bi[cA + 0] + bh[cA + 0];
      o.y = ac1 + bi[cA + 1] + bh[cA + 1];
      o.z = ac2 + bi[cA + 2] + bh[cA + 2];
      o.w = ac3 + bi[cA + 3] + bh[cA + 3];
      *reinterpret_cast<float4*>(&gates[(size_t)(m0 + tm) * 2048 + cA]) = o;
    }
    grid_barrier(barslots, barglines, gb + 1);

    // ============ P2: cell (into LDS) + [q | hpart] = h_i @ [Wha | Wout2] ====
    {
      const int mt = bid >> 4, nt = bid & 15;
      const int m0 = mt * 16;
      const bool isq = nt < 8;
      const float* Wp = isq ? Wha : (Wout + (size_t)H * H);
      const int n0 = (isq ? nt : nt - 8) * 64;
      float* Co = isq ? g_q : g_hp;

      for (int r = 0; r < 16; ++r) {
        size_t gbse = (size_t)(m0 + r) * 2048 + tid;
        float gi = sigmf(gates[gbse]);
        float gf = sigmf(gates[gbse + 512]);
        float gg = sigmf(gates[gbse + 1024]);
        float go = sigmf(gates[gbse + 1536]);
        float cn = gf * cr[(size_t)(m0 + r) * H + tid] + gi * gg;
        if (nt == 0) cw[(size_t)(m0 + r) * H + tid] = cn;
        sh.p2.hi[r][tid] = go * tanhf(cn);
      }
      __syncthreads();

      const int tm = tid >> 5;   // 0..15
      const int tn = tid & 31;   // 0..31
      float a0 = 0.f, a1 = 0.f;
      for (int kk = 0; kk < H; kk += 64) {
#pragma unroll
        for (int i = 0; i < 2; ++i) {
          int lin = tid + i * 512;
          int k = lin >> 4, c4 = (lin & 15) * 4;
          *reinterpret_cast<float4*>(&sh.p2.Bs[k][c4]) =
              *reinterpret_cast<const float4*>(Wp + (size_t)(kk + k) * H + n0 + c4);
        }
        __syncthreads();
#pragma unroll 8
        for (int k = 0; k < 64; ++k) {
          float av = sh.p2.hi[tm][kk + k];
          float2 b = *reinterpret_cast<const float2*>(&sh.p2.Bs[k][tn * 2]);
          a0 = fmaf(av, b.x, a0);
          a1 = fmaf(av, b.y, a1);
        }
        __syncthreads();
      }
      *reinterpret_cast<float2*>(&Co[(size_t)(m0 + tm) * H + n0 + tn * 2]) =
          make_float2(a0, a1);
    }
    grid_barrier(barslots, barglines, gb + 2);

    // ============ P3: fused scores+softmax+argmax+att, bitmask skip + prefetch
    {
      const int b = bid;
      const int wv = tid >> 6;   // wave 0..7, owns s in [wv*16, wv*16+16)
      const int ln = tid & 63;   // lane
      const int col = ln * 8;    // lane owns h-cols [col, col+8)

      const float* qb = g_q + (size_t)b * H + col;
      float4 qv0 = *reinterpret_cast<const float4*>(qb);
      float4 qv1 = *reinterpret_cast<const float4*>(qb + 4);
      float4 vv0 = *reinterpret_cast<const float4*>(v + col);
      float4 vv1 = *reinterpret_cast<const float4*>(v + col + 4);

      // wave's 16 mask values live in lanes 0..15 (broadcast via ballot/shfl)
      float mk16 = g_msk[(size_t)b * S + wv * 16 + (ln & 15)];
      uint32_t abits = (uint32_t)__ballot(mk16 != 0.f) & 0xFFFFu;
      if (ln < 16 && mk16 == 0.f) sh.p3.es[wv * 16 + ln] = 0.f;  // ref: exp(-1e9-m)->0

      float a0 = 0.f, a1 = 0.f, a2 = 0.f, a3 = 0.f;
      float a4 = 0.f, a5 = 0.f, a6 = 0.f, a7 = 0.f;
      const float* cpb = ctxp + ((size_t)b * S + wv * 16) * H + col;
      const float* cxb = ctx + ((size_t)b * S + wv * 16) * H + col;

      int i = -1;
      float4 P0, P1, X0, X1;
      if (abits) {
        i = (int)__builtin_ctz(abits);
        P0 = *reinterpret_cast<const float4*>(cpb + (size_t)i * H);
        P1 = *reinterpret_cast<const float4*>(cpb + (size_t)i * H + 4);
        X0 = *reinterpret_cast<const float4*>(cxb + (size_t)i * H);
        X1 = *reinterpret_cast<const float4*>(cxb + (size_t)i * H + 4);
      }
      while (i >= 0) {
        abits &= abits - 1;
        const int j = abits ? (int)__builtin_ctz(abits) : -1;
        float4 nP0, nP1, nX0, nX1;
        if (j >= 0) {  // prefetch next active row (wave-uniform branch)
          nP0 = *reinterpret_cast<const float4*>(cpb + (size_t)j * H);
          nP1 = *reinterpret_cast<const float4*>(cpb + (size_t)j * H + 4);
          nX0 = *reinterpret_cast<const float4*>(cxb + (size_t)j * H);
          nX1 = *reinterpret_cast<const float4*>(cxb + (size_t)j * H + 4);
        }
        float t0 = vv0.x * tanhf(P0.x + qv0.x);
        float t1 = vv0.y * tanhf(P0.y + qv0.y);
        float t2 = vv0.z * tanhf(P0.z + qv0.z);
        float t3 = vv0.w * tanhf(P0.w + qv0.w);
        float t4 = vv1.x * tanhf(P1.x + qv1.x);
        float t5 = vv1.y * tanhf(P1.y + qv1.y);
        float t6 = vv1.z * tanhf(P1.z + qv1.z);
        float t7 = vv1.w * tanhf(P1.w + qv1.w);
        float part = ((t0 + t1) + (t2 + t3)) + ((t4 + t5) + (t6 + t7));
#pragma unroll
        for (int o = 1; o < 64; o <<= 1) part += __shfl_xor(part, o);
        float e = expf(part);   // no max-subtraction: |score| <= ~8, safe
        if (ln == 0) sh.p3.es[wv * 16 + i] = e;
        a0 = fmaf(e, X0.x, a0);
        a1 = fmaf(e, X0.y, a1);
        a2 = fmaf(e, X0.z, a2);
        a3 = fmaf(e, X0.w, a3);
        a4 = fmaf(e, X1.x, a4);
        a5 = fmaf(e, X1.y, a5);
        a6 = fmaf(e, X1.z, a6);
        a7 = fmaf(e, X1.w, a7);
        i = j;
        P0 = nP0; P1 = nP1; X0 = nX0; X1 = nX1;
      }
      // wave partial of unnormalized att -> LDS (float4 stores)
      *reinterpret_cast<float4*>(&sh.p3.attp[wv][col]) = make_float4(a0, a1, a2, a3);
      *reinterpret_cast<float4*>(&sh.p3.attp[wv][col + 4]) = make_float4(a4, a5, a6, a7);
      __syncthreads();

      // sum of e over 128 s (threads 0..127)
      float e = (tid < 128) ? sh.p3.es[tid] : 0.f;
      float wsum = e;
#pragma unroll
      for (int o = 1; o < 64; o <<= 1) wsum += __shfl_xor(wsum, o);
      if (tid < 128 && (tid & 63) == 0) sh.p3.red[tid >> 6] = wsum;
      __syncthreads();
      const float sum = sh.p3.red[0] + sh.p3.red[1];

      // alpha + output write + argmax (masked entries are exactly 0)
      float a = e / sum;
      if (tid < 128) out[((size_t)b * S + t) * S + tid] = a;

      float mv = (tid < 128) ? a : -1.f;
      int mi = tid & 127;
#pragma unroll
      for (int o = 1; o < 64; o <<= 1) {
        float ov = __shfl_xor(mv, o);
        int oi = __shfl_xor(mi, o);
        if (ov > mv || (ov == mv && oi < mi)) { mv = ov; mi = oi; }
      }
      if (tid < 128 && (tid & 63) == 0) {
        sh.p3.red[2 + (tid >> 6)] = mv;
        sh.p3.redi[tid >> 6] = mi;
      }
      __syncthreads();
      if (tid == 0) {
        float bv = sh.p3.red[2];
        int bI = sh.p3.redi[0];
        if (sh.p3.red[3] > bv || (sh.p3.red[3] == bv && sh.p3.redi[1] < bI)) {
          bv = sh.p3.red[3];
          bI = sh.p3.redi[1];
        }
        out[(size_t)B * S * S + (size_t)b * S + t] = (float)bI;  // pointers[b,t]
        g_msk[(size_t)b * S + bI] = 0.f;
        g_sel[b] = bI;
      }

      // att finalize: att[b, tid] = (sum over 8 wave partials) / sum_e
      float acc = 0.f;
#pragma unroll
      for (int w = 0; w < 8; ++w) acc += sh.p3.attp[w][tid];
      g_att[(size_t)b * H + tid] = acc / sum;
    }
    grid_barrier(barslots, barglines, gb + 3);

    // ============ P4: h = tanh(att@Wout1 + hpart + bout) ============
    {
      const int m0 = (bid >> 5) * 32;   // 8 m-tiles of 32
      const int n0 = (bid & 31) * 16;   // 32 n-tiles of 16 (N=512)
      const int tm = tid >> 4;          // 0..31
      const int tn = tid & 15;          // 0..15
      float acc = 0.f;
      const int srow = tid >> 4, skq = (tid & 15) * 4;
      for (int kk = 0; kk < H; kk += 64) {
        float4 a4 = *reinterpret_cast<const float4*>(
            g_att + (size_t)(m0 + srow) * H + kk + skq);
        sh.p4.As[skq + 0][srow] = a4.x;
        sh.p4.As[skq + 1][srow] = a4.y;
        sh.p4.As[skq + 2][srow] = a4.z;
        sh.p4.As[skq + 3][srow] = a4.w;
        if (tid < 256) {
          int k = tid >> 2, c4 = (tid & 3) * 4;
          *reinterpret_cast<float4*>(&sh.p4.Bs[k][c4]) =
              *reinterpret_cast<const float4*>(Wout + (size_t)(kk + k) * H + n0 + c4);
        }
        __syncthreads();
#pragma unroll 8
        for (int k = 0; k < 64; ++k)
          acc = fmaf(sh.p4.As[k][tm], sh.p4.Bs[k][tn], acc);
        __syncthreads();
      }
      float x = acc + g_hp[(size_t)(m0 + tm) * H + n0 + tn] + bout[n0 + tn];
      g_h[(size_t)(m0 + tm) * H + n0 + tn] = tanhf(x);
    }
    grid_barrier(barslots, barglines, gb + 4);
  }
}

}  // namespace

// ---------------------------------------------------------------------------
extern "C" void kernel_launch(void* const* d_in, const int* in_sizes, int n_in,
                              void* d_out, int out_size, void* d_ws, size_t ws_size,
                              hipStream_t stream) {
  const float* emb  = (const float*)d_in[0];   // (B,S,H)
  const float* dec  = (const float*)d_in[1];   // (B,H)
  const float* h0   = (const float*)d_in[2];   // (B,H)
  const float* c0   = (const float*)d_in[3];   // (B,H)
  const float* ctx  = (const float*)d_in[4];   // (B,S,H)
  const float* Wi   = (const float*)d_in[5];   // (H,4H)
  const float* bi   = (const float*)d_in[6];   // (4H)
  const float* Wh   = (const float*)d_in[7];   // (H,4H)
  const float* bh   = (const float*)d_in[8];   // (4H)
  const float* Wctx = (const float*)d_in[9];   // (H,H)
  const float* Wha  = (const float*)d_in[10];  // (H,H)
  const float* v    = (const float*)d_in[11];  // (H)
  const float* Wout = (const float*)d_in[12];  // (2H,H)
  const float* bout = (const float*)d_in[13];  // (H)
  float* out = (float*)d_out;

  // workspace layout (floats)
  float* ws = (float*)d_ws;
  float* ctxp  = ws;                            // B*S*H = 16,777,216
  float* gates = ctxp + (size_t)B * S * H;      // B*4H
  float* g_h   = gates + (size_t)B * 4 * H;     // B*H
  float* c0buf = g_h + (size_t)B * H;           // B*H
  float* c1buf = c0buf + (size_t)B * H;         // B*H
  float* g_q   = c1buf + (size_t)B * H;         // B*H
  float* g_hp  = g_q + (size_t)B * H;           // B*H
  float* g_att = g_hp + (size_t)B * H;          // B*H
  float* g_msk = g_att + (size_t)B * H;         // B*S
  int*   g_sel = (int*)(g_msk + (size_t)B * S); // B
  int*   bar   = g_sel + B;                     // slots[256] + glines[256*16]

  init_kernel<<<(B * H + 511) / 512, 512, 0, stream>>>(g_h, c0buf, g_msk, bar, h0, c0);

  // ctx_proj = context @ Wctx   (32768 x 512, K=512)
  gemm_pre<128, 64, 8, 4, 16><<<dim3(H / 64, (B * S) / 128), 256, 0, stream>>>(
      ctx, Wctx, ctxp, B * S, H, H);

  decoder_fused<<<NBLK, NTHR, 0, stream>>>(
      emb, dec, ctx, Wi, bi, Wh, bh, Wha, v, Wout, bout, ctxp,
      gates, g_h, c0buf, c1buf, g_q, g_hp, g_att, g_msk, g_sel,
      bar, bar + NBLK, out);
}

// Round 5
// 19252.979 us; speedup vs baseline: 1.8584x; 1.8584x over previous
//
#include <hip/hip_runtime.h>
#include <cstddef>
#include <cstdint>

namespace {

constexpr int B = 256, S = 128, H = 512;
constexpr int NBLK = 256, NTHR = 512;
constexpr int GBLK = 32;          // blocks per group == rows per group
constexpr int SLOT_STRIDE = 16;   // ints per barrier slot line (64 B)

typedef float f4v __attribute__((ext_vector_type(4)));

__device__ __forceinline__ float sigmf(float x) { return 1.f / (1.f + expf(-x)); }

// L2-bypassing (device-coherent) scalar accesses: relaxed agent-scope atomics.
__device__ __forceinline__ float ld_sc(const float* p) {
  return __hip_atomic_load((float*)p, __ATOMIC_RELAXED, __HIP_MEMORY_SCOPE_AGENT);
}
__device__ __forceinline__ void st_sc(float* p, float x) {
  __hip_atomic_store(p, x, __ATOMIC_RELAXED, __HIP_MEMORY_SCOPE_AGENT);
}
__device__ __forceinline__ int ld_sci(const int* p) {
  return __hip_atomic_load((int*)p, __ATOMIC_RELAXED, __HIP_MEMORY_SCOPE_AGENT);
}
__device__ __forceinline__ void st_sci(int* p, int x) {
  __hip_atomic_store(p, x, __ATOMIC_RELAXED, __HIP_MEMORY_SCOPE_AGENT);
}

// ---------------------------------------------------------------------------
// init: g_h <- h0 ; barrier slots <- 0
// ---------------------------------------------------------------------------
__global__ __launch_bounds__(512) void init_kernel(float* __restrict__ h,
                                                   int* __restrict__ slots,
                                                   const float* __restrict__ h0) {
  int tid = blockIdx.x * 512 + threadIdx.x;
  if (tid < B * H) h[tid] = h0[tid];
  if (tid < NBLK * SLOT_STRIDE) slots[tid] = 0;
}

// ---------------------------------------------------------------------------
// Precompute GEMM: ctxp = context @ Wctx (fp32, k ascending per output).
// ---------------------------------------------------------------------------
template <int BM, int BN, int TM, int TN, int KT>
__global__ __launch_bounds__((BM / TM) * (BN / TN)) void gemm_pre(
    const float* __restrict__ A, const float* __restrict__ Bw,
    float* __restrict__ C, int M, int N, int K) {
  constexpr int THREADS = (BM / TM) * (BN / TN);
  const int tid = threadIdx.x;
  const int n0 = blockIdx.x * BN;
  const int m0 = blockIdx.y * BM;

  __shared__ float As[KT][BM + 4];
  __shared__ float Bs[KT][BN];

  float acc[TM][TN];
#pragma unroll
  for (int i = 0; i < TM; ++i)
#pragma unroll
    for (int jj = 0; jj < TN; ++jj) acc[i][jj] = 0.f;

  const int tn = tid % (BN / TN);
  const int tm = tid / (BN / TN);

  for (int kk = 0; kk < K; kk += KT) {
    for (int idx = tid; idx < BM * (KT / 4); idx += THREADS) {
      int row = idx / (KT / 4), kq = idx % (KT / 4);
      float4 a4 = *reinterpret_cast<const float4*>(A + (size_t)(m0 + row) * K + kk + kq * 4);
      As[kq * 4 + 0][row] = a4.x;
      As[kq * 4 + 1][row] = a4.y;
      As[kq * 4 + 2][row] = a4.z;
      As[kq * 4 + 3][row] = a4.w;
    }
    for (int idx = tid; idx < KT * (BN / 4); idx += THREADS) {
      int k = idx / (BN / 4), n4 = idx % (BN / 4);
      *reinterpret_cast<float4*>(&Bs[k][n4 * 4]) =
          *reinterpret_cast<const float4*>(Bw + (size_t)(kk + k) * N + n0 + n4 * 4);
    }
    __syncthreads();
#pragma unroll
    for (int k = 0; k < KT; ++k) {
      float a[TM], bb[TN];
#pragma unroll
      for (int i = 0; i < TM; ++i) a[i] = As[k][tm * TM + i];
#pragma unroll
      for (int jj = 0; jj < TN; ++jj) bb[jj] = Bs[k][tn * TN + jj];
#pragma unroll
      for (int i = 0; i < TM; ++i)
#pragma unroll
        for (int jj = 0; jj < TN; ++jj) acc[i][jj] = fmaf(a[i], bb[jj], acc[i][jj]);
    }
    __syncthreads();
  }
#pragma unroll
  for (int i = 0; i < TM; ++i)
#pragma unroll
    for (int jj = 0; jj < TN; ++jj)
      C[(size_t)(m0 + tm * TM + i) * N + n0 + tn * TN + jj] = acc[i][jj];
}

// ---------------------------------------------------------------------------
// Per-group barrier (32 blocks). No fences, no invalidates:
//  - __syncthreads() drains all waves' vmem (hipcc emits waitcnt before
//    s_barrier), so every sc1 payload store has reached the coherence point;
//  - leader stores generation into its OWN slot line (sc1);
//  - first 32 lanes poll the group's 32 slots (sc1, read-only).
// ---------------------------------------------------------------------------
__device__ __forceinline__ void group_barrier(int* slots, int grp, int j, int g) {
  __syncthreads();
  if (threadIdx.x == 0) st_sci(&slots[(grp * GBLK + j) * SLOT_STRIDE], g);
  if (threadIdx.x < GBLK) {
    while (ld_sci(&slots[(grp * GBLK + (int)threadIdx.x) * SLOT_STRIDE]) < g)
      __builtin_amdgcn_s_sleep(1);
  }
  __syncthreads();
  asm volatile("" ::: "memory");
}

// ---------------------------------------------------------------------------
// Persistent decoder. 8 independent groups of 32 blocks; group g owns batch
// rows [32g, 32g+32). Block (g, j) roles:
//   P1: gates+cell+h_i for 32 rows x (cols 16j..16j+16 of each gate quadrant)
//   P2: [q | hpart] = h_i @ [Wha | Wout2], cols 32j..32j+32 of N=1024
//   P3: attention/softmax/argmax for row bid (1 row per block)
//   P4: h = tanh(att@Wout1 + hpart + bout), cols 16j..16j+16
// c-state and mask live in LDS persistently. All mutable cross-block data
// moves via sc1 (ld_sc/st_sc); weights/ctx/ctxp stay plain-cached (L2-hot).
// ---------------------------------------------------------------------------
__global__ __launch_bounds__(NTHR) void decoder_fused(
    const float* __restrict__ emb, const float* __restrict__ dec,
    const float* __restrict__ ctx, const float* __restrict__ Wi,
    const float* __restrict__ bi, const float* __restrict__ Wh,
    const float* __restrict__ bh, const float* __restrict__ Wha,
    const float* __restrict__ v, const float* __restrict__ Wout,
    const float* __restrict__ bout, const float* __restrict__ c0,
    const float* __restrict__ ctxp, float* __restrict__ g_h,
    float* __restrict__ g_hi, float* __restrict__ g_q,
    float* __restrict__ g_hp, float* __restrict__ g_att,
    int* __restrict__ g_sel, int* __restrict__ slots,
    float* __restrict__ out) {
  const int bid = blockIdx.x;
  const int tid = threadIdx.x;
  const int grp = bid >> 5, j = bid & 31;
  const int r0 = grp * GBLK;   // first batch row of this group
  const int rb = bid;          // P3 row

  __shared__ float cslab[GBLK][17];  // persistent c state (rows x 16 cols)
  __shared__ float maskS[S];         // persistent mask for row rb
  __shared__ int selS[GBLK];
  __shared__ float red[4];
  __shared__ int redi[2];
  __shared__ union {
    struct { float As[64][34]; float Bs[64][64]; float gT[64][33]; } p1;  // 33.5 KB
    struct { float hiS[GBLK][516]; float Bs2[512][32]; } p2;              // 129 KB
    struct { float qsS[512]; float es[S]; float attp[8][516]; } p3;       // 19 KB
    struct { float attS[GBLK][516]; float Bs4[512][16]; } p4;             // 97 KB
  } sh;

  // persistent state init
  {
    int row = tid >> 4, u = tid & 15;
    cslab[row][u] = c0[(size_t)(r0 + row) * H + (j << 4) + u];
  }
  if (tid < S) maskS[tid] = 1.f;

  for (int t = 0; t < S; ++t) {
    const int gb = t * 4;

    // ===== P1: gates = [h|x] @ [Wh;Wi] + biases, then cell -> h_i =====
    {
      if (t > 0 && tid < GBLK) selS[tid] = ld_sci(&g_sel[r0 + tid]);
      __syncthreads();
      const int tm = tid >> 5, tn = tid & 31;  // 2 rows x 2 vcols per thread
      float a00 = 0.f, a01 = 0.f, a10 = 0.f, a11 = 0.f;
      float pa[4], pb[8];
      // prefetch chunk 0 (k 0..63 -> h rows, Wh)
      {
#pragma unroll
        for (int i = 0; i < 4; ++i) {
          int idx = tid + i * 512, row = idx >> 6, k = idx & 63;
          pa[i] = ld_sc(&g_h[(size_t)(r0 + row) * H + k]);
        }
#pragma unroll
        for (int i = 0; i < 8; ++i) {
          int idx = tid + i * 512, ko = idx >> 6, vc = idx & 63;
          pb[i] = Wh[(size_t)ko * 2048 + ((vc >> 4) << 9) + (j << 4) + (vc & 15)];
        }
      }
      for (int c = 0; c < 16; ++c) {
#pragma unroll
        for (int i = 0; i < 4; ++i) {
          int idx = tid + i * 512;
          sh.p1.As[idx & 63][idx >> 6] = pa[i];
        }
#pragma unroll
        for (int i = 0; i < 8; ++i) {
          int idx = tid + i * 512;
          sh.p1.Bs[idx >> 6][idx & 63] = pb[i];
        }
        __syncthreads();
        if (c < 15) {
          const int kk = (c + 1) * 64;
          if (kk < 512) {
#pragma unroll
            for (int i = 0; i < 4; ++i) {
              int idx = tid + i * 512, row = idx >> 6, k = kk + (idx & 63);
              pa[i] = ld_sc(&g_h[(size_t)(r0 + row) * H + k]);
            }
          } else if (t == 0) {
#pragma unroll
            for (int i = 0; i < 4; ++i) {
              int idx = tid + i * 512, row = idx >> 6, k = kk - 512 + (idx & 63);
              pa[i] = dec[(size_t)(r0 + row) * H + k];
            }
          } else {
#pragma unroll
            for (int i = 0; i < 4; ++i) {
              int idx = tid + i * 512, row = idx >> 6, k = kk - 512 + (idx & 63);
              pa[i] = emb[((size_t)(r0 + row) * S + selS[row]) * H + k];
            }
          }
          const float* W = (kk < 512) ? (Wh + (size_t)kk * 2048)
                                      : (Wi + (size_t)(kk - 512) * 2048);
#pragma unroll
          for (int i = 0; i < 8; ++i) {
            int idx = tid + i * 512, ko = idx >> 6, vc = idx & 63;
            pb[i] = W[(size_t)ko * 2048 + ((vc >> 4) << 9) + (j << 4) + (vc & 15)];
          }
        }
#pragma unroll 8
        for (int k = 0; k < 64; ++k) {
          float2 a = *reinterpret_cast<const float2*>(&sh.p1.As[k][tm * 2]);
          float2 b = *reinterpret_cast<const float2*>(&sh.p1.Bs[k][tn * 2]);
          a00 = fmaf(a.x, b.x, a00);
          a01 = fmaf(a.x, b.y, a01);
          a10 = fmaf(a.y, b.x, a10);
          a11 = fmaf(a.y, b.y, a11);
        }
        __syncthreads();
      }
      // gates tile (+bias) into LDS
      {
        int v0 = tn * 2, rw = tm * 2;
#pragma unroll
        for (int e = 0; e < 2; ++e) {
          int vc = v0 + e;
          int col = ((vc >> 4) << 9) + (j << 4) + (vc & 15);
          float bb = bi[col] + bh[col];
          sh.p1.gT[vc][rw] = (e ? a01 : a00) + bb;
          sh.p1.gT[vc][rw + 1] = (e ? a11 : a10) + bb;
        }
      }
      __syncthreads();
      // LSTM cell (sigmoid on all four gates, incl. cell gate)
      {
        int row = tid >> 4, u = tid & 15;
        float gi = sigmf(sh.p1.gT[u][row]);
        float gf = sigmf(sh.p1.gT[u + 16][row]);
        float gg = sigmf(sh.p1.gT[u + 32][row]);
        float go = sigmf(sh.p1.gT[u + 48][row]);
        float cn = gf * cslab[row][u] + gi * gg;
        cslab[row][u] = cn;
        st_sc(&g_hi[(size_t)(r0 + row) * H + (j << 4) + u], go * tanhf(cn));
      }
    }
    group_barrier(slots, grp, j, gb + 1);

    // ===== P2: [q | hpart] = h_i @ [Wha | Wout2], 32-col slab =====
    {
#pragma unroll
      for (int i = 0; i < 32; ++i)
        sh.p2.hiS[i][tid] = ld_sc(&g_hi[(size_t)(r0 + i) * H + tid]);
      const float* Wp;
      int c0c;
      if (j < 16) {
        Wp = Wha;
        c0c = 32 * j;
      } else {
        Wp = Wout + (size_t)512 * 512;  // Wout2 = rows 512..1024
        c0c = 32 * j - 512;
      }
#pragma unroll
      for (int i = 0; i < 32; ++i) {
        int k = i * 16 + (tid >> 5), cc = tid & 31;
        sh.p2.Bs2[k][cc] = Wp[(size_t)k * 512 + c0c + cc];
      }
      __syncthreads();
      const int row = tid >> 4, cp = tid & 15;
      float q0 = 0.f, q1 = 0.f;
#pragma unroll 8
      for (int k = 0; k < 512; ++k) {
        float a = sh.p2.hiS[row][k];
        float2 b = *reinterpret_cast<const float2*>(&sh.p2.Bs2[k][cp * 2]);
        q0 = fmaf(a, b.x, q0);
        q1 = fmaf(a, b.y, q1);
      }
      float* Co = (j < 16) ? g_q : g_hp;
      int col = c0c + cp * 2;
      st_sc(&Co[(size_t)(r0 + row) * H + col], q0);
      st_sc(&Co[(size_t)(r0 + row) * H + col + 1], q1);
    }
    group_barrier(slots, grp, j, gb + 2);

    // ===== P3: scores+softmax+argmax+att for row rb =====
    {
      sh.p3.qsS[tid] = ld_sc(&g_q[(size_t)rb * H + tid]);
      __syncthreads();
      const int wv = tid >> 6, ln = tid & 63, col = ln * 8;
      f4v qv0 = *reinterpret_cast<const f4v*>(&sh.p3.qsS[col]);
      f4v qv1 = *reinterpret_cast<const f4v*>(&sh.p3.qsS[col + 4]);
      f4v vv0 = *reinterpret_cast<const f4v*>(v + col);
      f4v vv1 = *reinterpret_cast<const f4v*>(v + col + 4);
      float mk16 = maskS[(wv << 4) + (ln & 15)];

      float a0 = 0.f, a1 = 0.f, a2 = 0.f, a3 = 0.f;
      float a4 = 0.f, a5 = 0.f, a6 = 0.f, a7 = 0.f;
      const float* cpb = ctxp + ((size_t)rb * S + (wv << 4)) * H + col;
      const float* cxb = ctx + ((size_t)rb * S + (wv << 4)) * H + col;

      for (int i = 0; i < 16; ++i) {
        float mk = __shfl(mk16, i);
        if (mk != 0.f) {
          f4v p0 = __builtin_nontemporal_load((const f4v*)(cpb + (size_t)i * H));
          f4v p1 = __builtin_nontemporal_load((const f4v*)(cpb + (size_t)i * H + 4));
          f4v x0 = __builtin_nontemporal_load((const f4v*)(cxb + (size_t)i * H));
          f4v x1 = __builtin_nontemporal_load((const f4v*)(cxb + (size_t)i * H + 4));
          float t0 = vv0[0] * tanhf(p0[0] + qv0[0]);
          float t1 = vv0[1] * tanhf(p0[1] + qv0[1]);
          float t2 = vv0[2] * tanhf(p0[2] + qv0[2]);
          float t3 = vv0[3] * tanhf(p0[3] + qv0[3]);
          float t4 = vv1[0] * tanhf(p1[0] + qv1[0]);
          float t5 = vv1[1] * tanhf(p1[1] + qv1[1]);
          float t6 = vv1[2] * tanhf(p1[2] + qv1[2]);
          float t7 = vv1[3] * tanhf(p1[3] + qv1[3]);
          float part = ((t0 + t1) + (t2 + t3)) + ((t4 + t5) + (t6 + t7));
#pragma unroll
          for (int o = 1; o < 64; o <<= 1) part += __shfl_xor(part, o);
          float e = expf(part);  // no max-subtraction: |score| small, safe
          if (ln == 0) sh.p3.es[(wv << 4) + i] = e;
          a0 = fmaf(e, x0[0], a0);
          a1 = fmaf(e, x0[1], a1);
          a2 = fmaf(e, x0[2], a2);
          a3 = fmaf(e, x0[3], a3);
          a4 = fmaf(e, x1[0], a4);
          a5 = fmaf(e, x1[1], a5);
          a6 = fmaf(e, x1[2], a6);
          a7 = fmaf(e, x1[3], a7);
        } else if (ln == 0) {
          sh.p3.es[(wv << 4) + i] = 0.f;  // ref: exp(-1e9-m) underflows to 0
        }
      }
      {
        f4v w0 = {a0, a1, a2, a3}, w1 = {a4, a5, a6, a7};
        *reinterpret_cast<f4v*>(&sh.p3.attp[wv][col]) = w0;
        *reinterpret_cast<f4v*>(&sh.p3.attp[wv][col + 4]) = w1;
      }
      __syncthreads();

      float e = (tid < S) ? sh.p3.es[tid] : 0.f;
      float wsum = e;
#pragma unroll
      for (int o = 1; o < 64; o <<= 1) wsum += __shfl_xor(wsum, o);
      if (tid < S && (tid & 63) == 0) red[tid >> 6] = wsum;
      __syncthreads();
      const float sum = red[0] + red[1];

      float a = e / sum;
      if (tid < S) out[((size_t)rb * S + t) * S + tid] = a;

      float mv = (tid < S) ? a : -1.f;
      int mi = tid & (S - 1);
#pragma unroll
      for (int o = 1; o < 64; o <<= 1) {
        float ov = __shfl_xor(mv, o);
        int oi = __shfl_xor(mi, o);
        if (ov > mv || (ov == mv && oi < mi)) { mv = ov; mi = oi; }
      }
      if (tid < S && (tid & 63) == 0) {
        red[2 + (tid >> 6)] = mv;
        redi[tid >> 6] = mi;
      }
      __syncthreads();
      if (tid == 0) {
        float bv = red[2];
        int bI = redi[0];
        if (red[3] > bv || (red[3] == bv && redi[1] < bI)) {
          bv = red[3];
          bI = redi[1];
        }
        out[(size_t)B * S * S + (size_t)rb * S + t] = (float)bI;  // pointer
        maskS[bI] = 0.f;
        st_sci(&g_sel[rb], bI);
      }

      float acc = 0.f;
#pragma unroll
      for (int w = 0; w < 8; ++w) acc += sh.p3.attp[w][tid];
      st_sc(&g_att[(size_t)rb * H + tid], acc / sum);
    }
    group_barrier(slots, grp, j, gb + 3);

    // ===== P4: h = tanh(att @ Wout1 + hpart + bout), 16-col slab =====
    {
#pragma unroll
      for (int i = 0; i < 32; ++i)
        sh.p4.attS[i][tid] = ld_sc(&g_att[(size_t)(r0 + i) * H + tid]);
#pragma unroll
      for (int i = 0; i < 16; ++i) {
        int k = i * 32 + (tid >> 4), cc = tid & 15;
        sh.p4.Bs4[k][cc] = Wout[(size_t)k * 512 + (j << 4) + cc];
      }
      __syncthreads();
      const int row = tid >> 4, cc = tid & 15;
      float acc = 0.f;
#pragma unroll 8
      for (int k = 0; k < 512; ++k)
        acc = fmaf(sh.p4.attS[row][k], sh.p4.Bs4[k][cc], acc);
      int col = (j << 4) + cc;
      float hp = ld_sc(&g_hp[(size_t)(r0 + row) * H + col]);
      float hv = tanhf(acc + hp + bout[col]);
      st_sc(&g_h[(size_t)(r0 + row) * H + col], hv);
    }
    group_barrier(slots, grp, j, gb + 4);
  }
}

}  // namespace

// ---------------------------------------------------------------------------
extern "C" void kernel_launch(void* const* d_in, const int* in_sizes, int n_in,
                              void* d_out, int out_size, void* d_ws, size_t ws_size,
                              hipStream_t stream) {
  const float* emb  = (const float*)d_in[0];   // (B,S,H)
  const float* dec  = (const float*)d_in[1];   // (B,H)
  const float* h0   = (const float*)d_in[2];   // (B,H)
  const float* c0   = (const float*)d_in[3];   // (B,H)
  const float* ctx  = (const float*)d_in[4];   // (B,S,H)
  const float* Wi   = (const float*)d_in[5];   // (H,4H)
  const float* bi   = (const float*)d_in[6];   // (4H)
  const float* Wh   = (const float*)d_in[7];   // (H,4H)
  const float* bh   = (const float*)d_in[8];   // (4H)
  const float* Wctx = (const float*)d_in[9];   // (H,H)
  const float* Wha  = (const float*)d_in[10];  // (H,H)
  const float* v    = (const float*)d_in[11];  // (H)
  const float* Wout = (const float*)d_in[12];  // (2H,H)
  const float* bout = (const float*)d_in[13];  // (H)
  float* out = (float*)d_out;

  // workspace layout (floats)
  float* ws = (float*)d_ws;
  float* ctxp  = ws;                            // B*S*H
  float* g_h   = ctxp + (size_t)B * S * H;      // B*H
  float* g_hi  = g_h + (size_t)B * H;           // B*H
  float* g_q   = g_hi + (size_t)B * H;          // B*H
  float* g_hp  = g_q + (size_t)B * H;           // B*H
  float* g_att = g_hp + (size_t)B * H;          // B*H
  int*   g_sel = (int*)(g_att + (size_t)B * H); // B
  int*   slots = g_sel + B;                     // NBLK*SLOT_STRIDE

  init_kernel<<<(B * H + 511) / 512, 512, 0, stream>>>(g_h, slots, h0);

  // ctx_proj = context @ Wctx   (32768 x 512, K=512)
  gemm_pre<128, 128, 8, 8, 16><<<dim3(H / 128, (B * S) / 128), 256, 0, stream>>>(
      ctx, Wctx, ctxp, B * S, H, H);

  decoder_fused<<<NBLK, NTHR, 0, stream>>>(
      emb, dec, ctx, Wi, bi, Wh, bh, Wha, v, Wout, bout, c0,
      ctxp, g_h, g_hi, g_q, g_hp, g_att, g_sel, slots, out);
}

// Round 6
// 12791.677 us; speedup vs baseline: 2.7971x; 1.5051x over previous
//
#include <hip/hip_runtime.h>
#include <cstddef>
#include <cstdint>

namespace {

constexpr int B = 256, S = 128, H = 512;
constexpr int NBLK = 256, NTHR = 512;
constexpr int GBLK = 32;          // blocks per group == rows per group
constexpr int SLOT_STRIDE = 16;   // ints per barrier slot line (64 B)

typedef float f4v __attribute__((ext_vector_type(4)));

__device__ __forceinline__ float sigmf(float x) { return 1.f / (1.f + expf(-x)); }

// --- device-coherent scalar (sc1) accesses for tiny payloads ---
__device__ __forceinline__ int ld_sci(const int* p) {
  return __hip_atomic_load((int*)p, __ATOMIC_RELAXED, __HIP_MEMORY_SCOPE_AGENT);
}
__device__ __forceinline__ void st_sci(int* p, int x) {
  __hip_atomic_store(p, x, __ATOMIC_RELAXED, __HIP_MEMORY_SCOPE_AGENT);
}

// --- wide device-coherent transfers (sc0 sc1 = bypass L1+L2, coherence pt) ---
__device__ __forceinline__ void ld4cc(f4v* d, const float* p) {
  asm volatile("global_load_dwordx4 %0, %1, off sc0 sc1" : "=&v"(*d) : "v"(p));
}
__device__ __forceinline__ void st4cc(float* p, f4v x) {
  asm volatile("global_store_dwordx4 %0, %1, off sc0 sc1" :: "v"(p), "v"(x) : "memory");
}
__device__ __forceinline__ void vmwait0() {
  asm volatile("s_waitcnt vmcnt(0)" ::: "memory");
  __builtin_amdgcn_sched_barrier(0);
}

// ---------------------------------------------------------------------------
__global__ __launch_bounds__(512) void init_kernel(float* __restrict__ h,
                                                   int* __restrict__ slots,
                                                   const float* __restrict__ h0) {
  int tid = blockIdx.x * 512 + threadIdx.x;
  if (tid < B * H) h[tid] = h0[tid];
  if (tid < NBLK * SLOT_STRIDE) slots[tid] = 0;
}

// ---------------------------------------------------------------------------
// Precompute GEMM: ctxp = context @ Wctx (fp32, k ascending per output).
// ---------------------------------------------------------------------------
template <int BM, int BN, int TM, int TN, int KT>
__global__ __launch_bounds__((BM / TM) * (BN / TN)) void gemm_pre(
    const float* __restrict__ A, const float* __restrict__ Bw,
    float* __restrict__ C, int M, int N, int K) {
  constexpr int THREADS = (BM / TM) * (BN / TN);
  const int tid = threadIdx.x;
  const int n0 = blockIdx.x * BN;
  const int m0 = blockIdx.y * BM;

  __shared__ float As[KT][BM + 4];
  __shared__ float Bs[KT][BN];

  float acc[TM][TN];
#pragma unroll
  for (int i = 0; i < TM; ++i)
#pragma unroll
    for (int jj = 0; jj < TN; ++jj) acc[i][jj] = 0.f;

  const int tn = tid % (BN / TN);
  const int tm = tid / (BN / TN);

  for (int kk = 0; kk < K; kk += KT) {
    for (int idx = tid; idx < BM * (KT / 4); idx += THREADS) {
      int row = idx / (KT / 4), kq = idx % (KT / 4);
      float4 a4 = *reinterpret_cast<const float4*>(A + (size_t)(m0 + row) * K + kk + kq * 4);
      As[kq * 4 + 0][row] = a4.x;
      As[kq * 4 + 1][row] = a4.y;
      As[kq * 4 + 2][row] = a4.z;
      As[kq * 4 + 3][row] = a4.w;
    }
    for (int idx = tid; idx < KT * (BN / 4); idx += THREADS) {
      int k = idx / (BN / 4), n4 = idx % (BN / 4);
      *reinterpret_cast<float4*>(&Bs[k][n4 * 4]) =
          *reinterpret_cast<const float4*>(Bw + (size_t)(kk + k) * N + n0 + n4 * 4);
    }
    __syncthreads();
#pragma unroll
    for (int k = 0; k < KT; ++k) {
      float a[TM], bb[TN];
#pragma unroll
      for (int i = 0; i < TM; ++i) a[i] = As[k][tm * TM + i];
#pragma unroll
      for (int jj = 0; jj < TN; ++jj) bb[jj] = Bs[k][tn * TN + jj];
#pragma unroll
      for (int i = 0; i < TM; ++i)
#pragma unroll
        for (int jj = 0; jj < TN; ++jj) acc[i][jj] = fmaf(a[i], bb[jj], acc[i][jj]);
    }
    __syncthreads();
  }
#pragma unroll
  for (int i = 0; i < TM; ++i)
#pragma unroll
    for (int jj = 0; jj < TN; ++jj)
      C[(size_t)(m0 + tm * TM + i) * N + n0 + tn * TN + jj] = acc[i][jj];
}

// ---------------------------------------------------------------------------
// Per-group barrier (32 blocks): explicit vmcnt drain (covers asm cc stores),
// leader slot store, 32-lane poll. No fences, no cache invalidates.
// ---------------------------------------------------------------------------
__device__ __forceinline__ void group_barrier(int* slots, int grp, int j, int g) {
  asm volatile("s_waitcnt vmcnt(0)" ::: "memory");
  __syncthreads();
  if (threadIdx.x == 0) st_sci(&slots[(grp * GBLK + j) * SLOT_STRIDE], g);
  if (threadIdx.x < GBLK) {
    while (ld_sci(&slots[(grp * GBLK + (int)threadIdx.x) * SLOT_STRIDE]) < g)
      __builtin_amdgcn_s_sleep(1);
  }
  __syncthreads();
  asm volatile("" ::: "memory");
}

// ---------------------------------------------------------------------------
// Persistent decoder: 8 groups x 32 blocks; group owns rows [32g, 32g+32).
// All cross-block mutable data moves via wide sc0sc1; weights/ctx/ctxp cached.
// ---------------------------------------------------------------------------
__global__ __launch_bounds__(NTHR) void decoder_fused(
    const float* __restrict__ emb, const float* __restrict__ dec,
    const float* __restrict__ ctx, const float* __restrict__ Wi,
    const float* __restrict__ bi, const float* __restrict__ Wh,
    const float* __restrict__ bh, const float* __restrict__ Wha,
    const float* __restrict__ v, const float* __restrict__ Wout,
    const float* __restrict__ bout, const float* __restrict__ c0,
    const float* __restrict__ ctxp, float* __restrict__ g_h,
    float* __restrict__ g_hi, float* __restrict__ g_q,
    float* __restrict__ g_hp, float* __restrict__ g_att,
    int* __restrict__ g_sel, int* __restrict__ slots,
    float* __restrict__ out) {
  const int bid = blockIdx.x;
  const int tid = threadIdx.x;
  const int grp = bid >> 5, j = bid & 31;
  const int r0 = grp * GBLK;
  const int rb = bid;

  __shared__ float cslab[GBLK][17];
  __shared__ float maskS[S];
  __shared__ int selS[GBLK];
  __shared__ float red[4];
  __shared__ int redi[2];
  __shared__ union {
    struct { float As[64][34]; float Bs[64][64]; float gT[64][33]; float hiT[32][20]; } p1;
    struct { float hiS[32][516]; float Bs2[512][32]; float outT[32][36]; } p2;
    struct { float qsS[512]; float es[S]; float attp[8][516]; } p3;
    struct { float attS[32][516]; float Bs4[512][16]; float hpS[32][20]; float hT[32][20]; } p4;
  } sh;

  {
    int row = tid >> 4, u = tid & 15;
    cslab[row][u] = c0[(size_t)(r0 + row) * H + (j << 4) + u];
  }
  if (tid < S) maskS[tid] = 1.f;

  for (int t = 0; t < S; ++t) {
    const int gb = t * 4;

    // ===== P1: gates = [h|x] @ [Wh;Wi] + biases -> cell -> h_i (16 cols) =====
    {
      if (t > 0 && tid < GBLK) selS[tid] = ld_sci(&g_sel[r0 + tid]);
      __syncthreads();
      const int tm = tid >> 5, tn = tid & 31;
      float a00 = 0.f, a01 = 0.f, a10 = 0.f, a11 = 0.f;
      const int srow = tid >> 4;         // staging row 0..31
      const int skq = (tid & 15) * 4;    // staging k-quad

      const int k0 = tid >> 4, cq0 = tid & 15;
      const int col0 = ((cq0 >> 2) << 9) + (j << 4) + (cq0 & 3) * 4;
      const int k1 = (tid + 512) >> 4, cq1 = tid & 15;  // (tid+512)&15 == tid&15
      const int col1 = col0;

      f4v aH, bW0, bW1;
      // prologue: chunk 0 (h-part, Wh)
      ld4cc(&aH, &g_h[(size_t)(r0 + srow) * H + skq]);
      bW0 = *reinterpret_cast<const f4v*>(&Wh[(size_t)k0 * 2048 + col0]);
      bW1 = *reinterpret_cast<const f4v*>(&Wh[(size_t)k1 * 2048 + col1]);

      for (int c = 0; c < 16; ++c) {
        vmwait0();
        sh.p1.As[skq + 0][srow] = aH[0];
        sh.p1.As[skq + 1][srow] = aH[1];
        sh.p1.As[skq + 2][srow] = aH[2];
        sh.p1.As[skq + 3][srow] = aH[3];
        *reinterpret_cast<f4v*>(&sh.p1.Bs[k0][cq0 * 4]) = bW0;
        *reinterpret_cast<f4v*>(&sh.p1.Bs[k1][cq1 * 4]) = bW1;
        __syncthreads();
        if (c < 15) {
          const int kk = (c + 1) * 64;
          const float* Wp = (kk < 512) ? (Wh + (size_t)kk * 2048)
                                       : (Wi + (size_t)(kk - 512) * 2048);
          if (kk < 512) {
            ld4cc(&aH, &g_h[(size_t)(r0 + srow) * H + kk + skq]);
          } else if (t == 0) {
            aH = *reinterpret_cast<const f4v*>(
                &dec[(size_t)(r0 + srow) * H + (kk - 512) + skq]);
          } else {
            aH = *reinterpret_cast<const f4v*>(
                &emb[((size_t)(r0 + srow) * S + selS[srow]) * H + (kk - 512) + skq]);
          }
          bW0 = *reinterpret_cast<const f4v*>(&Wp[(size_t)k0 * 2048 + col0]);
          bW1 = *reinterpret_cast<const f4v*>(&Wp[(size_t)k1 * 2048 + col1]);
        }
#pragma unroll 8
        for (int k = 0; k < 64; ++k) {
          float2 a = *reinterpret_cast<const float2*>(&sh.p1.As[k][tm * 2]);
          float2 b = *reinterpret_cast<const float2*>(&sh.p1.Bs[k][tn * 2]);
          a00 = fmaf(a.x, b.x, a00);
          a01 = fmaf(a.x, b.y, a01);
          a10 = fmaf(a.y, b.x, a10);
          a11 = fmaf(a.y, b.y, a11);
        }
        __syncthreads();
      }
      // gates tile (+bias) into LDS
      {
        int v0 = tn * 2, rw = tm * 2;
#pragma unroll
        for (int e = 0; e < 2; ++e) {
          int vc = v0 + e;
          int col = ((vc >> 4) << 9) + (j << 4) + (vc & 15);
          float bb = bi[col] + bh[col];
          sh.p1.gT[vc][rw] = (e ? a01 : a00) + bb;
          sh.p1.gT[vc][rw + 1] = (e ? a11 : a10) + bb;
        }
      }
      __syncthreads();
      // LSTM cell (sigmoid on all four gates)
      {
        int row = tid >> 4, u = tid & 15;
        float gi = sigmf(sh.p1.gT[u][row]);
        float gf = sigmf(sh.p1.gT[u + 16][row]);
        float gg = sigmf(sh.p1.gT[u + 32][row]);
        float go = sigmf(sh.p1.gT[u + 48][row]);
        float cn = gf * cslab[row][u] + gi * gg;
        cslab[row][u] = cn;
        sh.p1.hiT[row][u] = go * tanhf(cn);
      }
      __syncthreads();
      if (tid < 128) {
        int rw = tid >> 2, uq = (tid & 3) * 4;
        f4v hv = {sh.p1.hiT[rw][uq], sh.p1.hiT[rw][uq + 1],
                  sh.p1.hiT[rw][uq + 2], sh.p1.hiT[rw][uq + 3]};
        st4cc(&g_hi[(size_t)(r0 + rw) * H + (j << 4) + uq], hv);
      }
    }
    group_barrier(slots, grp, j, gb + 1);

    // ===== P2: [q | hpart] = h_i @ [Wha | Wout2], 32-col slab =====
    {
      const float* Wp;
      int c0c;
      if (j < 16) { Wp = Wha; c0c = 32 * j; }
      else        { Wp = Wout + (size_t)H * H; c0c = 32 * j - 512; }

      f4v hbuf[8], wbuf[8];
#pragma unroll
      for (int i = 0; i < 8; ++i) {
        int idx = tid + i * 512;
        int row = idx >> 7, kq = (idx & 127) * 4;
        ld4cc(&hbuf[i], &g_hi[(size_t)(r0 + row) * H + kq]);
      }
#pragma unroll
      for (int i = 0; i < 8; ++i) {
        int lin = tid + i * 512;
        int k = lin >> 3, cq = lin & 7;
        wbuf[i] = *reinterpret_cast<const f4v*>(&Wp[(size_t)k * 512 + c0c + cq * 4]);
      }
      vmwait0();
#pragma unroll
      for (int i = 0; i < 8; ++i) {
        int idx = tid + i * 512;
        int row = idx >> 7, kq = (idx & 127) * 4;
        *reinterpret_cast<f4v*>(&sh.p2.hiS[row][kq]) = hbuf[i];
      }
#pragma unroll
      for (int i = 0; i < 8; ++i) {
        int lin = tid + i * 512;
        int k = lin >> 3, cq = lin & 7;
        *reinterpret_cast<f4v*>(&sh.p2.Bs2[k][cq * 4]) = wbuf[i];
      }
      __syncthreads();
      const int row = tid >> 4, cp = tid & 15;
      float q0 = 0.f, q1 = 0.f;
#pragma unroll 8
      for (int k = 0; k < 512; ++k) {
        float a = sh.p2.hiS[row][k];
        float2 b = *reinterpret_cast<const float2*>(&sh.p2.Bs2[k][cp * 2]);
        q0 = fmaf(a, b.x, q0);
        q1 = fmaf(a, b.y, q1);
      }
      sh.p2.outT[row][cp * 2] = q0;
      sh.p2.outT[row][cp * 2 + 1] = q1;
      __syncthreads();
      float* Co = (j < 16) ? g_q : g_hp;
      if (tid < 256) {
        int rw = tid >> 3, cq = (tid & 7) * 4;
        f4v ov = {sh.p2.outT[rw][cq], sh.p2.outT[rw][cq + 1],
                  sh.p2.outT[rw][cq + 2], sh.p2.outT[rw][cq + 3]};
        st4cc(&Co[(size_t)(r0 + rw) * H + c0c + cq], ov);
      }
    }
    group_barrier(slots, grp, j, gb + 2);

    // ===== P3: scores+softmax+argmax+att for row rb (plain cached streams) ===
    {
      if (tid < 128) {
        f4v qv;
        ld4cc(&qv, &g_q[(size_t)rb * H + tid * 4]);
        vmwait0();
        *reinterpret_cast<f4v*>(&sh.p3.qsS[tid * 4]) = qv;
      } else {
        vmwait0();
      }
      __syncthreads();
      const int wv = tid >> 6, ln = tid & 63, col = ln * 8;
      float4 qv0 = *reinterpret_cast<const float4*>(&sh.p3.qsS[col]);
      float4 qv1 = *reinterpret_cast<const float4*>(&sh.p3.qsS[col + 4]);
      float4 vv0 = *reinterpret_cast<const float4*>(v + col);
      float4 vv1 = *reinterpret_cast<const float4*>(v + col + 4);
      float mk16 = maskS[(wv << 4) + (ln & 15)];
      uint32_t abits = (uint32_t)__ballot(mk16 != 0.f) & 0xFFFFu;
      if (ln < 16 && mk16 == 0.f) sh.p3.es[(wv << 4) + ln] = 0.f;

      float a0 = 0.f, a1 = 0.f, a2 = 0.f, a3 = 0.f;
      float a4 = 0.f, a5 = 0.f, a6 = 0.f, a7 = 0.f;
      const float* cpb = ctxp + ((size_t)rb * S + (wv << 4)) * H + col;
      const float* cxb = ctx + ((size_t)rb * S + (wv << 4)) * H + col;

      int i = -1;
      float4 P0, P1, X0, X1;
      if (abits) {
        i = (int)__builtin_ctz(abits);
        P0 = *reinterpret_cast<const float4*>(cpb + (size_t)i * H);
        P1 = *reinterpret_cast<const float4*>(cpb + (size_t)i * H + 4);
        X0 = *reinterpret_cast<const float4*>(cxb + (size_t)i * H);
        X1 = *reinterpret_cast<const float4*>(cxb + (size_t)i * H + 4);
      }
      while (i >= 0) {
        abits &= abits - 1;
        const int jn = abits ? (int)__builtin_ctz(abits) : -1;
        float4 nP0, nP1, nX0, nX1;
        if (jn >= 0) {
          nP0 = *reinterpret_cast<const float4*>(cpb + (size_t)jn * H);
          nP1 = *reinterpret_cast<const float4*>(cpb + (size_t)jn * H + 4);
          nX0 = *reinterpret_cast<const float4*>(cxb + (size_t)jn * H);
          nX1 = *reinterpret_cast<const float4*>(cxb + (size_t)jn * H + 4);
        }
        float t0 = vv0.x * tanhf(P0.x + qv0.x);
        float t1 = vv0.y * tanhf(P0.y + qv0.y);
        float t2 = vv0.z * tanhf(P0.z + qv0.z);
        float t3 = vv0.w * tanhf(P0.w + qv0.w);
        float t4 = vv1.x * tanhf(P1.x + qv1.x);
        float t5 = vv1.y * tanhf(P1.y + qv1.y);
        float t6 = vv1.z * tanhf(P1.z + qv1.z);
        float t7 = vv1.w * tanhf(P1.w + qv1.w);
        float part = ((t0 + t1) + (t2 + t3)) + ((t4 + t5) + (t6 + t7));
#pragma unroll
        for (int o = 1; o < 64; o <<= 1) part += __shfl_xor(part, o);
        float e = expf(part);
        if (ln == 0) sh.p3.es[(wv << 4) + i] = e;
        a0 = fmaf(e, X0.x, a0);
        a1 = fmaf(e, X0.y, a1);
        a2 = fmaf(e, X0.z, a2);
        a3 = fmaf(e, X0.w, a3);
        a4 = fmaf(e, X1.x, a4);
        a5 = fmaf(e, X1.y, a5);
        a6 = fmaf(e, X1.z, a6);
        a7 = fmaf(e, X1.w, a7);
        i = jn;
        P0 = nP0; P1 = nP1; X0 = nX0; X1 = nX1;
      }
      {
        f4v w0 = {a0, a1, a2, a3}, w1 = {a4, a5, a6, a7};
        *reinterpret_cast<f4v*>(&sh.p3.attp[wv][col]) = w0;
        *reinterpret_cast<f4v*>(&sh.p3.attp[wv][col + 4]) = w1;
      }
      __syncthreads();

      float e = (tid < S) ? sh.p3.es[tid] : 0.f;
      float wsum = e;
#pragma unroll
      for (int o = 1; o < 64; o <<= 1) wsum += __shfl_xor(wsum, o);
      if (tid < S && (tid & 63) == 0) red[tid >> 6] = wsum;
      __syncthreads();
      const float sum = red[0] + red[1];

      float a = e / sum;
      if (tid < S) out[((size_t)rb * S + t) * S + tid] = a;

      float mv = (tid < S) ? a : -1.f;
      int mi = tid & (S - 1);
#pragma unroll
      for (int o = 1; o < 64; o <<= 1) {
        float ov = __shfl_xor(mv, o);
        int oi = __shfl_xor(mi, o);
        if (ov > mv || (ov == mv && oi < mi)) { mv = ov; mi = oi; }
      }
      if (tid < S && (tid & 63) == 0) {
        red[2 + (tid >> 6)] = mv;
        redi[tid >> 6] = mi;
      }
      __syncthreads();
      if (tid == 0) {
        float bv = red[2];
        int bI = redi[0];
        if (red[3] > bv || (red[3] == bv && redi[1] < bI)) {
          bv = red[3];
          bI = redi[1];
        }
        out[(size_t)B * S * S + (size_t)rb * S + t] = (float)bI;
        maskS[bI] = 0.f;
        st_sci(&g_sel[rb], bI);
      }

      float acc = 0.f;
#pragma unroll
      for (int w = 0; w < 8; ++w) acc += sh.p3.attp[w][tid];
      sh.p3.attp[0][tid] = acc / sum;
      __syncthreads();
      if (tid < 128) {
        f4v av = {sh.p3.attp[0][tid * 4], sh.p3.attp[0][tid * 4 + 1],
                  sh.p3.attp[0][tid * 4 + 2], sh.p3.attp[0][tid * 4 + 3]};
        st4cc(&g_att[(size_t)rb * H + tid * 4], av);
      }
    }
    group_barrier(slots, grp, j, gb + 3);

    // ===== P4: h = tanh(att @ Wout1 + hpart + bout), 16-col slab =====
    {
      f4v abuf[8], wb[4], hpv;
#pragma unroll
      for (int i = 0; i < 8; ++i) {
        int idx = tid + i * 512;
        int row = idx >> 7, kq = (idx & 127) * 4;
        ld4cc(&abuf[i], &g_att[(size_t)(r0 + row) * H + kq]);
      }
      if (tid < 128)
        ld4cc(&hpv, &g_hp[(size_t)(r0 + (tid >> 2)) * H + (j << 4) + (tid & 3) * 4]);
#pragma unroll
      for (int i = 0; i < 4; ++i) {
        int lin = tid + i * 512;
        int k = lin >> 2, cq = lin & 3;
        wb[i] = *reinterpret_cast<const f4v*>(&Wout[(size_t)k * 512 + (j << 4) + cq * 4]);
      }
      vmwait0();
#pragma unroll
      for (int i = 0; i < 8; ++i) {
        int idx = tid + i * 512;
        int row = idx >> 7, kq = (idx & 127) * 4;
        *reinterpret_cast<f4v*>(&sh.p4.attS[row][kq]) = abuf[i];
      }
      if (tid < 128)
        *reinterpret_cast<f4v*>(&sh.p4.hpS[tid >> 2][(tid & 3) * 4]) = hpv;
#pragma unroll
      for (int i = 0; i < 4; ++i) {
        int lin = tid + i * 512;
        int k = lin >> 2, cq = lin & 3;
        *reinterpret_cast<f4v*>(&sh.p4.Bs4[k][cq * 4]) = wb[i];
      }
      __syncthreads();
      const int row = tid >> 4, cc = tid & 15;
      float acc = 0.f;
#pragma unroll 8
      for (int k = 0; k < 512; ++k)
        acc = fmaf(sh.p4.attS[row][k], sh.p4.Bs4[k][cc], acc);
      int col = (j << 4) + cc;
      sh.p4.hT[row][cc] = tanhf(acc + sh.p4.hpS[row][cc] + bout[col]);
      __syncthreads();
      if (tid < 128) {
        int rw = tid >> 2, uq = (tid & 3) * 4;
        f4v hv = {sh.p4.hT[rw][uq], sh.p4.hT[rw][uq + 1],
                  sh.p4.hT[rw][uq + 2], sh.p4.hT[rw][uq + 3]};
        st4cc(&g_h[(size_t)(r0 + rw) * H + (j << 4) + uq], hv);
      }
    }
    group_barrier(slots, grp, j, gb + 4);
  }
}

}  // namespace

// ---------------------------------------------------------------------------
extern "C" void kernel_launch(void* const* d_in, const int* in_sizes, int n_in,
                              void* d_out, int out_size, void* d_ws, size_t ws_size,
                              hipStream_t stream) {
  const float* emb  = (const float*)d_in[0];
  const float* dec  = (const float*)d_in[1];
  const float* h0   = (const float*)d_in[2];
  const float* c0   = (const float*)d_in[3];
  const float* ctx  = (const float*)d_in[4];
  const float* Wi   = (const float*)d_in[5];
  const float* bi   = (const float*)d_in[6];
  const float* Wh   = (const float*)d_in[7];
  const float* bh   = (const float*)d_in[8];
  const float* Wctx = (const float*)d_in[9];
  const float* Wha  = (const float*)d_in[10];
  const float* v    = (const float*)d_in[11];
  const float* Wout = (const float*)d_in[12];
  const float* bout = (const float*)d_in[13];
  float* out = (float*)d_out;

  float* ws = (float*)d_ws;
  float* ctxp  = ws;                            // B*S*H
  float* g_h   = ctxp + (size_t)B * S * H;      // B*H
  float* g_hi  = g_h + (size_t)B * H;           // B*H
  float* g_q   = g_hi + (size_t)B * H;          // B*H
  float* g_hp  = g_q + (size_t)B * H;           // B*H
  float* g_att = g_hp + (size_t)B * H;          // B*H
  int*   g_sel = (int*)(g_att + (size_t)B * H); // B
  int*   slots = g_sel + B;                     // NBLK*SLOT_STRIDE

  init_kernel<<<(B * H + 511) / 512, 512, 0, stream>>>(g_h, slots, h0);

  gemm_pre<128, 128, 8, 8, 16><<<dim3(H / 128, (B * S) / 128), 256, 0, stream>>>(
      ctx, Wctx, ctxp, B * S, H, H);

  decoder_fused<<<NBLK, NTHR, 0, stream>>>(
      emb, dec, ctx, Wi, bi, Wh, bh, Wha, v, Wout, bout, c0,
      ctxp, g_h, g_hi, g_q, g_hp, g_att, g_sel, slots, out);
}

// Round 7
// 10629.317 us; speedup vs baseline: 3.3662x; 1.2034x over previous
//
#include <hip/hip_runtime.h>
#include <cstddef>
#include <cstdint>

namespace {

constexpr int B = 256, S = 128, H = 512;
constexpr int NBLK = 256, NTHR = 512;
constexpr int GBLK = 32;
constexpr int SLOT_STRIDE = 16;

typedef float f4v __attribute__((ext_vector_type(4)));

__device__ __forceinline__ float sigmf(float x) { return 1.f / (1.f + expf(-x)); }

__device__ __forceinline__ int ld_sci(const int* p) {
  return __hip_atomic_load((int*)p, __ATOMIC_RELAXED, __HIP_MEMORY_SCOPE_AGENT);
}
__device__ __forceinline__ void st_sci(int* p, int x) {
  __hip_atomic_store(p, x, __ATOMIC_RELAXED, __HIP_MEMORY_SCOPE_AGENT);
}
__device__ __forceinline__ void ld4cc(f4v* d, const float* p) {
  asm volatile("global_load_dwordx4 %0, %1, off sc0 sc1" : "=&v"(*d) : "v"(p));
}
__device__ __forceinline__ void st4cc(float* p, f4v x) {
  asm volatile("global_store_dwordx4 %0, %1, off sc0 sc1" :: "v"(p), "v"(x) : "memory");
}
__device__ __forceinline__ void vmwait0() {
  asm volatile("s_waitcnt vmcnt(0)" ::: "memory");
  __builtin_amdgcn_sched_barrier(0);
}

// ---------------------------------------------------------------------------
// init: h0 -> g_hTc (k-major chunk layout [g][ch][k][36]); slots <- 0
// ---------------------------------------------------------------------------
__global__ __launch_bounds__(512) void init_kernel(float* __restrict__ g_hTc,
                                                   int* __restrict__ slots,
                                                   const float* __restrict__ h0) {
  int tid = blockIdx.x * 512 + threadIdx.x;
  if (tid < B * H) {
    int r = tid & 31, k = (tid >> 5) & 63, ch = (tid >> 11) & 7, g = tid >> 14;
    g_hTc[(((size_t)(g * 8 + ch) * 64) + k) * 36 + r] =
        h0[(size_t)(g * 32 + r) * H + ch * 64 + k];
  }
  if (tid < NBLK * SLOT_STRIDE) slots[tid] = 0;
}

// ---------------------------------------------------------------------------
// Precompute GEMM: ctxp = context @ Wctx
// ---------------------------------------------------------------------------
template <int BM, int BN, int TM, int TN, int KT>
__global__ __launch_bounds__((BM / TM) * (BN / TN)) void gemm_pre(
    const float* __restrict__ A, const float* __restrict__ Bw,
    float* __restrict__ C, int M, int N, int K) {
  constexpr int THREADS = (BM / TM) * (BN / TN);
  const int tid = threadIdx.x;
  const int n0 = blockIdx.x * BN;
  const int m0 = blockIdx.y * BM;

  __shared__ float As[KT][BM + 4];
  __shared__ float Bs[KT][BN];

  float acc[TM][TN];
#pragma unroll
  for (int i = 0; i < TM; ++i)
#pragma unroll
    for (int jj = 0; jj < TN; ++jj) acc[i][jj] = 0.f;

  const int tn = tid % (BN / TN);
  const int tm = tid / (BN / TN);

  for (int kk = 0; kk < K; kk += KT) {
    for (int idx = tid; idx < BM * (KT / 4); idx += THREADS) {
      int row = idx / (KT / 4), kq = idx % (KT / 4);
      float4 a4 = *reinterpret_cast<const float4*>(A + (size_t)(m0 + row) * K + kk + kq * 4);
      As[kq * 4 + 0][row] = a4.x;
      As[kq * 4 + 1][row] = a4.y;
      As[kq * 4 + 2][row] = a4.z;
      As[kq * 4 + 3][row] = a4.w;
    }
    for (int idx = tid; idx < KT * (BN / 4); idx += THREADS) {
      int k = idx / (BN / 4), n4 = idx % (BN / 4);
      *reinterpret_cast<float4*>(&Bs[k][n4 * 4]) =
          *reinterpret_cast<const float4*>(Bw + (size_t)(kk + k) * N + n0 + n4 * 4);
    }
    __syncthreads();
#pragma unroll
    for (int k = 0; k < KT; ++k) {
      float a[TM], bb[TN];
#pragma unroll
      for (int i = 0; i < TM; ++i) a[i] = As[k][tm * TM + i];
#pragma unroll
      for (int jj = 0; jj < TN; ++jj) bb[jj] = Bs[k][tn * TN + jj];
#pragma unroll
      for (int i = 0; i < TM; ++i)
#pragma unroll
        for (int jj = 0; jj < TN; ++jj) acc[i][jj] = fmaf(a[i], bb[jj], acc[i][jj]);
    }
    __syncthreads();
  }
#pragma unroll
  for (int i = 0; i < TM; ++i)
#pragma unroll
    for (int jj = 0; jj < TN; ++jj)
      C[(size_t)(m0 + tm * TM + i) * N + n0 + tn * TN + jj] = acc[i][jj];
}

// ---------------------------------------------------------------------------
// Per-group barrier (unchanged from R6: no fences, sc1 slot stores + polls)
// ---------------------------------------------------------------------------
__device__ __forceinline__ void group_barrier(int* slots, int grp, int j, int g) {
  asm volatile("s_waitcnt vmcnt(0)" ::: "memory");
  __syncthreads();
  if (threadIdx.x == 0) st_sci(&slots[(grp * GBLK + j) * SLOT_STRIDE], g);
  if (threadIdx.x < GBLK) {
    while (ld_sci(&slots[(grp * GBLK + (int)threadIdx.x) * SLOT_STRIDE]) < g)
      __builtin_amdgcn_s_sleep(1);
  }
  __syncthreads();
  asm volatile("" ::: "memory");
}

// ---------------------------------------------------------------------------
// Persistent decoder. Waves act as k-slices in P1/P2/P4 (cross-wave reduce in
// LDS); mutable cross-block traffic via wide sc0sc1; weights/ctx/ctxp cached.
// ---------------------------------------------------------------------------
__global__ __launch_bounds__(NTHR) void decoder_fused(
    const float* __restrict__ emb, const float* __restrict__ dec,
    const float* __restrict__ ctx, const float* __restrict__ Wi,
    const float* __restrict__ bi, const float* __restrict__ Wh,
    const float* __restrict__ bh, const float* __restrict__ Wha,
    const float* __restrict__ v, const float* __restrict__ Wout,
    const float* __restrict__ bout, const float* __restrict__ c0,
    const float* __restrict__ ctxp, float* __restrict__ g_hTc,
    float* __restrict__ g_hiTc, float* __restrict__ g_q,
    float* __restrict__ g_hp, float* __restrict__ g_att,
    int* __restrict__ g_sel, int* __restrict__ slots,
    float* __restrict__ out) {
  const int bid = blockIdx.x, tid = threadIdx.x;
  const int grp = bid >> 5, j = bid & 31;
  const int r0 = grp * GBLK, rb = bid;
  const int wv = tid >> 6, ln = tid & 63;
  const int rg = ln >> 3, cg = ln & 7;

  __shared__ float cslab[GBLK][17];
  __shared__ float maskS[S];
  __shared__ int selS[GBLK];
  __shared__ float red[4];
  __shared__ int redi[2];

  __shared__ union {
    struct {
      union {
        struct { float As[64][36]; float Bs[64][64]; } st;   // 25.6 KB
        float prt[8][32][68];                                 // 69.6 KB
      };
      float gT[64][33];   // 8.4 KB
      float hiT[32][20];  // 2.5 KB
    } p1;
    struct {
      union { float hiT[512][36]; float prt[8][32][36]; };    // 73.7 KB
      float Bs2[512][32];                                      // 65.5 KB
    } p2;
    struct { float qsS[512]; float es[S]; float attp[8][516]; } p3;
    struct {
      union { float attT[512][36]; float prt[8][32][20]; };   // 73.7 KB
      float Bs4[512][16];                                      // 32.8 KB
      float hpS[32][20];
      float hT[32][20];
    } p4;
  } sh;

  const float* g_hTc_g = g_hTc + (size_t)grp * 8 * 64 * 36;
  float* g_hiTc_g = g_hiTc + (size_t)grp * 512 * 36;

  // persistent state
  {
    int row = tid >> 4, u = tid & 15;
    cslab[row][u] = c0[(size_t)(r0 + row) * H + (j << 4) + u];
  }
  if (tid < S) maskS[tid] = 1.f;

  for (int t = 0; t < S; ++t) {
    const int gb = t * 4;

    // ===== P1: gates = [h|x]@[Wh;Wi]+biases -> cell -> h_i (block: 64 cols) ==
    {
      if (t > 0 && tid < GBLK) selS[tid] = ld_sci(&g_sel[r0 + tid]);
      __syncthreads();

      float acc[4][8];
#pragma unroll
      for (int i2 = 0; i2 < 4; ++i2)
#pragma unroll
        for (int j2 = 0; j2 < 8; ++j2) acc[i2][j2] = 0.f;

      const int bk0 = tid >> 4, bm = tid & 15;       // Bs staging decomposition
      const int bq = bm >> 2, boff = (bm & 3) * 4;

      for (int part = 0; part < 2; ++part) {
        const float* Wp = part ? Wi : Wh;
        for (int ch = 0; ch < 8; ++ch) {
          const int kk = ch * 64;
          // ---- stage Bs (plain cached W loads; layout linear) ----
          f4v w0c = *reinterpret_cast<const f4v*>(
              Wp + (size_t)(kk + bk0) * 2048 + bq * 512 + (j << 4) + boff);
          f4v w1c = *reinterpret_cast<const f4v*>(
              Wp + (size_t)(kk + 32 + bk0) * 2048 + bq * 512 + (j << 4) + boff);
          if (part == 0) {
            // ---- stage As: linear f4 copy from k-major g_hTc chunk ----
            const float* src = g_hTc_g + (size_t)ch * 2304;
            f4v sv0, sv1;
            ld4cc(&sv0, src + tid * 4);
            const bool ex = tid < 64;
            if (ex) ld4cc(&sv1, src + (512 + tid) * 4);
            vmwait0();
            float* asf = &sh.p1.st.As[0][0];
            *reinterpret_cast<f4v*>(asf + tid * 4) = sv0;
            if (ex) *reinterpret_cast<f4v*>(asf + (512 + tid) * 4) = sv1;
          } else {
            // ---- stage As: transpose from row-major x (dec/emb gather) ----
            const int srow = tid >> 4, m = tid & 15;
            const float* xr = (t == 0)
                ? dec + (size_t)(r0 + srow) * H
                : emb + ((size_t)(r0 + srow) * S + selS[srow]) * H;
            float4 xv = *reinterpret_cast<const float4*>(xr + kk + 4 * m);
            sh.p1.st.As[4 * m + 0][srow] = xv.x;
            sh.p1.st.As[4 * m + 1][srow] = xv.y;
            sh.p1.st.As[4 * m + 2][srow] = xv.z;
            sh.p1.st.As[4 * m + 3][srow] = xv.w;
          }
          *reinterpret_cast<f4v*>(&sh.p1.st.Bs[bk0][4 * bm]) = w0c;
          *reinterpret_cast<f4v*>(&sh.p1.st.Bs[32 + bk0][4 * bm]) = w1c;
          __syncthreads();
          // ---- compute: wave wv handles k in [8wv, 8wv+8) of this chunk ----
          const int kb = 8 * wv;
#pragma unroll
          for (int kx = 0; kx < 8; ++kx) {
            const int k = kb + kx;
            f4v a = *reinterpret_cast<const f4v*>(&sh.p1.st.As[k][4 * rg]);
            f4v b0 = *reinterpret_cast<const f4v*>(&sh.p1.st.Bs[k][4 * cg]);
            f4v b1 = *reinterpret_cast<const f4v*>(&sh.p1.st.Bs[k][32 + 4 * cg]);
#pragma unroll
            for (int i2 = 0; i2 < 4; ++i2) {
#pragma unroll
              for (int j2 = 0; j2 < 4; ++j2) {
                acc[i2][j2] = fmaf(a[i2], b0[j2], acc[i2][j2]);
                acc[i2][4 + j2] = fmaf(a[i2], b1[j2], acc[i2][4 + j2]);
              }
            }
          }
          __syncthreads();
        }
      }
      // ---- cross-wave reduce via LDS partials ----
#pragma unroll
      for (int i2 = 0; i2 < 4; ++i2) {
        f4v w0 = {acc[i2][0], acc[i2][1], acc[i2][2], acc[i2][3]};
        f4v w1 = {acc[i2][4], acc[i2][5], acc[i2][6], acc[i2][7]};
        *reinterpret_cast<f4v*>(&sh.p1.prt[wv][4 * rg + i2][4 * cg]) = w0;
        *reinterpret_cast<f4v*>(&sh.p1.prt[wv][4 * rg + i2][32 + 4 * cg]) = w1;
      }
      __syncthreads();
      {
        const int r = tid >> 4, c = 4 * (tid & 15);
        f4v s = *reinterpret_cast<const f4v*>(&sh.p1.prt[0][r][c]);
#pragma unroll
        for (int w = 1; w < 8; ++w) {
          f4v p = *reinterpret_cast<const f4v*>(&sh.p1.prt[w][r][c]);
          s[0] += p[0]; s[1] += p[1]; s[2] += p[2]; s[3] += p[3];
        }
#pragma unroll
        for (int e = 0; e < 4; ++e) {
          int vc = c + e;
          int gcol = ((vc >> 4) << 9) + (j << 4) + (vc & 15);
          sh.p1.gT[vc][r] = s[e] + bi[gcol] + bh[gcol];
        }
      }
      __syncthreads();
      // ---- LSTM cell (sigmoid on all 4 gates) ----
      {
        int row = tid >> 4, u = tid & 15;
        float gi = sigmf(sh.p1.gT[u][row]);
        float gf = sigmf(sh.p1.gT[u + 16][row]);
        float gg = sigmf(sh.p1.gT[u + 32][row]);
        float go = sigmf(sh.p1.gT[u + 48][row]);
        float cn = gf * cslab[row][u] + gi * gg;
        cslab[row][u] = cn;
        sh.p1.hiT[row][u] = go * tanhf(cn);
      }
      __syncthreads();
      // ---- h_i -> g_hiTc (k-major, f4 over rows) ----
      if (tid < 128) {
        int u = tid >> 3, rw = tid & 7;
        f4v hv = {sh.p1.hiT[4 * rw + 0][u], sh.p1.hiT[4 * rw + 1][u],
                  sh.p1.hiT[4 * rw + 2][u], sh.p1.hiT[4 * rw + 3][u]};
        st4cc(&g_hiTc_g[((j << 4) + u) * 36 + 4 * rw], hv);
      }
    }
    group_barrier(slots, grp, j, gb + 1);

    // ===== P2: [q | hpart] = h_i @ [Wha | Wout2], 32-col slab ===============
    {
      // stage hiT (linear f4 copy) + W slab
      {
        f4v bufs[9];
#pragma unroll
        for (int i2 = 0; i2 < 9; ++i2) {
          int lin = tid + i2 * 512;
          ld4cc(&bufs[i2], g_hiTc_g + lin * 4);
        }
        vmwait0();
        float* hf = &sh.p2.hiT[0][0];
#pragma unroll
        for (int i2 = 0; i2 < 9; ++i2) {
          int lin = tid + i2 * 512;
          *reinterpret_cast<f4v*>(hf + lin * 4) = bufs[i2];
        }
      }
      const float* Wp; int c0c;
      if (j < 16) { Wp = Wha; c0c = 32 * j; }
      else        { Wp = Wout + (size_t)H * H; c0c = 32 * j - 512; }
#pragma unroll
      for (int i2 = 0; i2 < 8; ++i2) {
        int lin = tid + i2 * 512;
        int k = lin >> 3, cq = (lin & 7) * 4;
        *reinterpret_cast<f4v*>(&sh.p2.Bs2[k][cq]) =
            *reinterpret_cast<const f4v*>(Wp + (size_t)k * 512 + c0c + cq);
      }
      __syncthreads();
      float qa[4][4];
#pragma unroll
      for (int i2 = 0; i2 < 4; ++i2)
#pragma unroll
        for (int j2 = 0; j2 < 4; ++j2) qa[i2][j2] = 0.f;
      const int kb = 64 * wv;
#pragma unroll 8
      for (int kx = 0; kx < 64; ++kx) {
        const int k = kb + kx;
        f4v a = *reinterpret_cast<const f4v*>(&sh.p2.hiT[k][4 * rg]);
        f4v b = *reinterpret_cast<const f4v*>(&sh.p2.Bs2[k][4 * cg]);
#pragma unroll
        for (int i2 = 0; i2 < 4; ++i2)
#pragma unroll
          for (int j2 = 0; j2 < 4; ++j2) qa[i2][j2] = fmaf(a[i2], b[j2], qa[i2][j2]);
      }
      __syncthreads();
#pragma unroll
      for (int i2 = 0; i2 < 4; ++i2) {
        f4v w0 = {qa[i2][0], qa[i2][1], qa[i2][2], qa[i2][3]};
        *reinterpret_cast<f4v*>(&sh.p2.prt[wv][4 * rg + i2][4 * cg]) = w0;
      }
      __syncthreads();
      if (tid < 256) {
        int r = tid >> 3, c4 = (tid & 7) * 4;
        f4v s = *reinterpret_cast<const f4v*>(&sh.p2.prt[0][r][c4]);
#pragma unroll
        for (int w = 1; w < 8; ++w) {
          f4v p = *reinterpret_cast<const f4v*>(&sh.p2.prt[w][r][c4]);
          s[0] += p[0]; s[1] += p[1]; s[2] += p[2]; s[3] += p[3];
        }
        float* Co = (j < 16) ? g_q : g_hp;
        st4cc(&Co[(size_t)(r0 + r) * H + c0c + c4], s);
      }
    }
    group_barrier(slots, grp, j, gb + 2);

    // ===== P3: scores+softmax+argmax+att for row rb (3-deep pipeline) =======
    {
      {
        f4v qv;
        const bool qld = tid < 128;
        if (qld) ld4cc(&qv, &g_q[(size_t)rb * H + tid * 4]);
        vmwait0();
        if (qld) *reinterpret_cast<f4v*>(&sh.p3.qsS[tid * 4]) = qv;
      }
      __syncthreads();
      const int col = ln * 8;
      float4 qv0 = *reinterpret_cast<const float4*>(&sh.p3.qsS[col]);
      float4 qv1 = *reinterpret_cast<const float4*>(&sh.p3.qsS[col + 4]);
      float4 vv0 = *reinterpret_cast<const float4*>(v + col);
      float4 vv1 = *reinterpret_cast<const float4*>(v + col + 4);
      float mk16 = maskS[(wv << 4) + (ln & 15)];
      uint32_t abits = (uint32_t)__ballot(mk16 != 0.f) & 0xFFFFu;
      if (ln < 16 && mk16 == 0.f) sh.p3.es[(wv << 4) + ln] = 0.f;

      float a0 = 0.f, a1 = 0.f, a2 = 0.f, a3 = 0.f;
      float a4 = 0.f, a5 = 0.f, a6 = 0.f, a7 = 0.f;
      const float* cpb = ctxp + ((size_t)rb * S + (wv << 4)) * H + col;
      const float* cxb = ctx + ((size_t)rb * S + (wv << 4)) * H + col;

      uint32_t bb = abits;
      auto pop = [&]() -> int {
        if (!bb) return -1;
        int r = (int)__builtin_ctz(bb);
        bb &= bb - 1;
        return r;
      };
      auto p3load = [&](float4& P0, float4& P1, float4& X0, float4& X1, int i) {
        P0 = *reinterpret_cast<const float4*>(cpb + (size_t)i * H);
        P1 = *reinterpret_cast<const float4*>(cpb + (size_t)i * H + 4);
        X0 = *reinterpret_cast<const float4*>(cxb + (size_t)i * H);
        X1 = *reinterpret_cast<const float4*>(cxb + (size_t)i * H + 4);
      };
      auto p3comp = [&](const float4& P0, const float4& P1, const float4& X0,
                        const float4& X1, int i) {
        float t0 = vv0.x * tanhf(P0.x + qv0.x);
        float t1 = vv0.y * tanhf(P0.y + qv0.y);
        float t2 = vv0.z * tanhf(P0.z + qv0.z);
        float t3 = vv0.w * tanhf(P0.w + qv0.w);
        float t4 = vv1.x * tanhf(P1.x + qv1.x);
        float t5 = vv1.y * tanhf(P1.y + qv1.y);
        float t6 = vv1.z * tanhf(P1.z + qv1.z);
        float t7 = vv1.w * tanhf(P1.w + qv1.w);
        float part = ((t0 + t1) + (t2 + t3)) + ((t4 + t5) + (t6 + t7));
#pragma unroll
        for (int o = 1; o < 64; o <<= 1) part += __shfl_xor(part, o);
        float e2 = expf(part);
        if (ln == 0) sh.p3.es[(wv << 4) + i] = e2;
        a0 = fmaf(e2, X0.x, a0);
        a1 = fmaf(e2, X0.y, a1);
        a2 = fmaf(e2, X0.z, a2);
        a3 = fmaf(e2, X0.w, a3);
        a4 = fmaf(e2, X1.x, a4);
        a5 = fmaf(e2, X1.y, a5);
        a6 = fmaf(e2, X1.z, a6);
        a7 = fmaf(e2, X1.w, a7);
      };

      float4 A0, A1, A2, A3, B0, B1, B2, B3, C0, C1, C2, C3;
      int ia = pop(), ib = pop(), ic = pop();
      if (ia >= 0) p3load(A0, A1, A2, A3, ia);
      if (ib >= 0) p3load(B0, B1, B2, B3, ib);
      if (ic >= 0) p3load(C0, C1, C2, C3, ic);
      while (ia >= 0) {
        p3comp(A0, A1, A2, A3, ia);
        ia = pop();
        if (ia >= 0) p3load(A0, A1, A2, A3, ia);
        if (ib < 0) break;
        p3comp(B0, B1, B2, B3, ib);
        ib = pop();
        if (ib >= 0) p3load(B0, B1, B2, B3, ib);
        if (ic < 0) break;
        p3comp(C0, C1, C2, C3, ic);
        ic = pop();
        if (ic >= 0) p3load(C0, C1, C2, C3, ic);
      }
      {
        f4v w0 = {a0, a1, a2, a3}, w1 = {a4, a5, a6, a7};
        *reinterpret_cast<f4v*>(&sh.p3.attp[wv][col]) = w0;
        *reinterpret_cast<f4v*>(&sh.p3.attp[wv][col + 4]) = w1;
      }
      __syncthreads();

      float e = (tid < S) ? sh.p3.es[tid] : 0.f;
      float wsum = e;
#pragma unroll
      for (int o = 1; o < 64; o <<= 1) wsum += __shfl_xor(wsum, o);
      if (tid < S && (tid & 63) == 0) red[tid >> 6] = wsum;
      __syncthreads();
      const float sum = red[0] + red[1];

      float a = e / sum;
      if (tid < 32) {
        f4v ev = *reinterpret_cast<const f4v*>(&sh.p3.es[tid * 4]);
        f4v av = {ev[0] / sum, ev[1] / sum, ev[2] / sum, ev[3] / sum};
        *reinterpret_cast<f4v*>(&out[((size_t)rb * S + t) * S + tid * 4]) = av;
      }

      float mv = (tid < S) ? a : -1.f;
      int mi = tid & (S - 1);
#pragma unroll
      for (int o = 1; o < 64; o <<= 1) {
        float ov = __shfl_xor(mv, o);
        int oi = __shfl_xor(mi, o);
        if (ov > mv || (ov == mv && oi < mi)) { mv = ov; mi = oi; }
      }
      if (tid < S && (tid & 63) == 0) {
        red[2 + (tid >> 6)] = mv;
        redi[tid >> 6] = mi;
      }
      __syncthreads();
      if (tid == 0) {
        float bv = red[2];
        int bI = redi[0];
        if (red[3] > bv || (red[3] == bv && redi[1] < bI)) {
          bv = red[3];
          bI = redi[1];
        }
        out[(size_t)B * S * S + (size_t)rb * S + t] = (float)bI;
        maskS[bI] = 0.f;
        st_sci(&g_sel[rb], bI);
      }

      float accA = 0.f;
#pragma unroll
      for (int w = 0; w < 8; ++w) accA += sh.p3.attp[w][tid];
      sh.p3.attp[0][tid] = accA / sum;
      __syncthreads();
      if (tid < 128) {
        f4v av = {sh.p3.attp[0][tid * 4], sh.p3.attp[0][tid * 4 + 1],
                  sh.p3.attp[0][tid * 4 + 2], sh.p3.attp[0][tid * 4 + 3]};
        st4cc(&g_att[(size_t)rb * H + tid * 4], av);
      }
    }
    group_barrier(slots, grp, j, gb + 3);

    // ===== P4: h = tanh(att@Wout1 + hpart + bout), 16-col slab ==============
    {
      // stage attT (transpose), Bs4, hpS
      {
        const int srow = tid >> 4, m = tid & 15;
        f4v ab[8];
#pragma unroll
        for (int i2 = 0; i2 < 8; ++i2)
          ld4cc(&ab[i2], &g_att[(size_t)(r0 + srow) * H + i2 * 64 + 4 * m]);
        f4v hpv;
        const bool hld = tid < 128;
        if (hld)
          ld4cc(&hpv, &g_hp[(size_t)(r0 + (tid >> 2)) * H + (j << 4) + (tid & 3) * 4]);
#pragma unroll
        for (int i2 = 0; i2 < 4; ++i2) {
          int lin = tid + i2 * 512;
          int k = lin >> 2, cq = (lin & 3) * 4;
          *reinterpret_cast<f4v*>(&sh.p4.Bs4[k][cq]) =
              *reinterpret_cast<const f4v*>(Wout + (size_t)k * 512 + (j << 4) + cq);
        }
        vmwait0();
#pragma unroll
        for (int i2 = 0; i2 < 8; ++i2) {
#pragma unroll
          for (int e = 0; e < 4; ++e)
            sh.p4.attT[i2 * 64 + 4 * m + e][srow] = ab[i2][e];
        }
        if (hld)
          *reinterpret_cast<f4v*>(&sh.p4.hpS[tid >> 2][(tid & 3) * 4]) = hpv;
      }
      __syncthreads();
      float pa[4][2];
#pragma unroll
      for (int i2 = 0; i2 < 4; ++i2) { pa[i2][0] = 0.f; pa[i2][1] = 0.f; }
      const int kb = 64 * wv;
#pragma unroll 8
      for (int kx = 0; kx < 64; ++kx) {
        const int k = kb + kx;
        f4v a = *reinterpret_cast<const f4v*>(&sh.p4.attT[k][4 * rg]);
        float2 b2 = *reinterpret_cast<const float2*>(&sh.p4.Bs4[k][2 * cg]);
#pragma unroll
        for (int i2 = 0; i2 < 4; ++i2) {
          pa[i2][0] = fmaf(a[i2], b2.x, pa[i2][0]);
          pa[i2][1] = fmaf(a[i2], b2.y, pa[i2][1]);
        }
      }
      __syncthreads();
#pragma unroll
      for (int i2 = 0; i2 < 4; ++i2)
        *reinterpret_cast<float2*>(&sh.p4.prt[wv][4 * rg + i2][2 * cg]) =
            make_float2(pa[i2][0], pa[i2][1]);
      __syncthreads();
      {
        int r = tid >> 4, cc = tid & 15;
        float s2 = sh.p4.prt[0][r][cc];
#pragma unroll
        for (int w = 1; w < 8; ++w) s2 += sh.p4.prt[w][r][cc];
        int gcol = (j << 4) + cc;
        sh.p4.hT[r][cc] = tanhf(s2 + sh.p4.hpS[r][cc] + bout[gcol]);
      }
      __syncthreads();
      if (tid < 128) {
        int u = tid >> 3, rw = tid & 7;
        f4v hv = {sh.p4.hT[4 * rw + 0][u], sh.p4.hT[4 * rw + 1][u],
                  sh.p4.hT[4 * rw + 2][u], sh.p4.hT[4 * rw + 3][u]};
        int kloc = (j << 4) + u;
        int ch = kloc >> 6, k = kloc & 63;
        st4cc(&g_hTc[(((size_t)grp * 8 + ch) * 64 + k) * 36 + 4 * rw], hv);
      }
    }
    group_barrier(slots, grp, j, gb + 4);
  }
}

}  // namespace

// ---------------------------------------------------------------------------
extern "C" void kernel_launch(void* const* d_in, const int* in_sizes, int n_in,
                              void* d_out, int out_size, void* d_ws, size_t ws_size,
                              hipStream_t stream) {
  const float* emb  = (const float*)d_in[0];
  const float* dec  = (const float*)d_in[1];
  const float* h0   = (const float*)d_in[2];
  const float* c0   = (const float*)d_in[3];
  const float* ctx  = (const float*)d_in[4];
  const float* Wi   = (const float*)d_in[5];
  const float* bi   = (const float*)d_in[6];
  const float* Wh   = (const float*)d_in[7];
  const float* bh   = (const float*)d_in[8];
  const float* Wctx = (const float*)d_in[9];
  const float* Wha  = (const float*)d_in[10];
  const float* v    = (const float*)d_in[11];
  const float* Wout = (const float*)d_in[12];
  const float* bout = (const float*)d_in[13];
  float* out = (float*)d_out;

  float* ws = (float*)d_ws;
  float* ctxp   = ws;                                  // B*S*H
  float* g_hTc  = ctxp + (size_t)B * S * H;            // 8*8*64*36 = 147456
  float* g_hiTc = g_hTc + (size_t)8 * 8 * 64 * 36;     // 8*512*36  = 147456
  float* g_q    = g_hiTc + (size_t)8 * 512 * 36;       // B*H
  float* g_hp   = g_q + (size_t)B * H;                 // B*H
  float* g_att  = g_hp + (size_t)B * H;                // B*H
  int*   g_sel  = (int*)(g_att + (size_t)B * H);       // B
  int*   slots  = g_sel + B;                           // NBLK*SLOT_STRIDE

  init_kernel<<<(B * H + 511) / 512, 512, 0, stream>>>(g_hTc, slots, h0);

  gemm_pre<128, 128, 8, 8, 16><<<dim3(H / 128, (B * S) / 128), 256, 0, stream>>>(
      ctx, Wctx, ctxp, B * S, H, H);

  decoder_fused<<<NBLK, NTHR, 0, stream>>>(
      emb, dec, ctx, Wi, bi, Wh, bh, Wha, v, Wout, bout, c0,
      ctxp, g_hTc, g_hiTc, g_q, g_hp, g_att, g_sel, slots, out);
}

// Round 8
// 9934.924 us; speedup vs baseline: 3.6014x; 1.0699x over previous
//
#include <hip/hip_runtime.h>
#include <cstddef>
#include <cstdint>

namespace {

constexpr int B = 256, S = 128, H = 512;
constexpr int NBLK = 256, NTHR = 512;
constexpr int GBLK = 32;
constexpr int SLOT_STRIDE = 16;

typedef float f4v __attribute__((ext_vector_type(4)));

constexpr float LOG2E = 1.4426950408889634f;

__device__ __forceinline__ float fexp2(float x) { return __builtin_amdgcn_exp2f(x); }
__device__ __forceinline__ float frcp(float x) { return __builtin_amdgcn_rcpf(x); }
// tanh(x) = 1 - 2/(e^{2x}+1); inf-safe both directions (rcp(inf)=0)
__device__ __forceinline__ float fast_tanh(float x) {
  float e = fexp2(x * (2.f * LOG2E));
  return fmaf(-2.f, frcp(e + 1.f), 1.f);
}
__device__ __forceinline__ float fast_sigm(float x) {
  return frcp(fexp2(-x * LOG2E) + 1.f);
}
__device__ __forceinline__ float fast_exp(float x) { return fexp2(x * LOG2E); }

// DPP 64-lane sum: full sum lands in lanes 48..63; broadcast via readlane(63).
template <int CTRL>
__device__ __forceinline__ float dpp_term(float x) {
  int yi = __builtin_amdgcn_update_dpp(0, __builtin_bit_cast(int, x), CTRL, 0xF, 0xF, true);
  return __builtin_bit_cast(float, yi);
}
__device__ __forceinline__ float wave_sum64_hi(float x) {
  x += dpp_term<0xB1>(x);    // quad_perm [1,0,3,2]  (xor 1)
  x += dpp_term<0x4E>(x);    // quad_perm [2,3,0,1]  (xor 2)
  x += dpp_term<0x141>(x);   // row_half_mirror      (xor 4)
  x += dpp_term<0x140>(x);   // row_mirror           (xor 8)
  x += dpp_term<0x142>(x);   // row_bcast15
  x += dpp_term<0x143>(x);   // row_bcast31
  return x;                  // lanes 48..63 hold the full 64-lane sum
}
__device__ __forceinline__ float bcast63(float x) {
  return __builtin_bit_cast(float,
      __builtin_amdgcn_readlane(__builtin_bit_cast(int, x), 63));
}

__device__ __forceinline__ int ld_sci(const int* p) {
  return __hip_atomic_load((int*)p, __ATOMIC_RELAXED, __HIP_MEMORY_SCOPE_AGENT);
}
__device__ __forceinline__ void st_sci(int* p, int x) {
  __hip_atomic_store(p, x, __ATOMIC_RELAXED, __HIP_MEMORY_SCOPE_AGENT);
}
__device__ __forceinline__ void ld4cc(f4v* d, const float* p) {
  asm volatile("global_load_dwordx4 %0, %1, off sc0 sc1" : "=&v"(*d) : "v"(p));
}
__device__ __forceinline__ void st4cc(float* p, f4v x) {
  asm volatile("global_store_dwordx4 %0, %1, off sc0 sc1" :: "v"(p), "v"(x) : "memory");
}
__device__ __forceinline__ void vmwait0() {
  asm volatile("s_waitcnt vmcnt(0)" ::: "memory");
  __builtin_amdgcn_sched_barrier(0);
}

// ---------------------------------------------------------------------------
// init: h0 -> g_hTc (k-major chunk layout [g][ch][k][36]); slots <- 0
// ---------------------------------------------------------------------------
__global__ __launch_bounds__(512) void init_kernel(float* __restrict__ g_hTc,
                                                   int* __restrict__ slots,
                                                   const float* __restrict__ h0) {
  int tid = blockIdx.x * 512 + threadIdx.x;
  if (tid < B * H) {
    int r = tid & 31, k = (tid >> 5) & 63, ch = (tid >> 11) & 7, g = tid >> 14;
    g_hTc[(((size_t)(g * 8 + ch) * 64) + k) * 36 + r] =
        h0[(size_t)(g * 32 + r) * H + ch * 64 + k];
  }
  if (tid < NBLK * SLOT_STRIDE) slots[tid] = 0;
}

// ---------------------------------------------------------------------------
// Precompute GEMM: ctxp = context @ Wctx
// ---------------------------------------------------------------------------
template <int BM, int BN, int TM, int TN, int KT>
__global__ __launch_bounds__((BM / TM) * (BN / TN)) void gemm_pre(
    const float* __restrict__ A, const float* __restrict__ Bw,
    float* __restrict__ C, int M, int N, int K) {
  constexpr int THREADS = (BM / TM) * (BN / TN);
  const int tid = threadIdx.x;
  const int n0 = blockIdx.x * BN;
  const int m0 = blockIdx.y * BM;

  __shared__ float As[KT][BM + 4];
  __shared__ float Bs[KT][BN];

  float acc[TM][TN];
#pragma unroll
  for (int i = 0; i < TM; ++i)
#pragma unroll
    for (int jj = 0; jj < TN; ++jj) acc[i][jj] = 0.f;

  const int tn = tid % (BN / TN);
  const int tm = tid / (BN / TN);

  for (int kk = 0; kk < K; kk += KT) {
    for (int idx = tid; idx < BM * (KT / 4); idx += THREADS) {
      int row = idx / (KT / 4), kq = idx % (KT / 4);
      float4 a4 = *reinterpret_cast<const float4*>(A + (size_t)(m0 + row) * K + kk + kq * 4);
      As[kq * 4 + 0][row] = a4.x;
      As[kq * 4 + 1][row] = a4.y;
      As[kq * 4 + 2][row] = a4.z;
      As[kq * 4 + 3][row] = a4.w;
    }
    for (int idx = tid; idx < KT * (BN / 4); idx += THREADS) {
      int k = idx / (BN / 4), n4 = idx % (BN / 4);
      *reinterpret_cast<float4*>(&Bs[k][n4 * 4]) =
          *reinterpret_cast<const float4*>(Bw + (size_t)(kk + k) * N + n0 + n4 * 4);
    }
    __syncthreads();
#pragma unroll
    for (int k = 0; k < KT; ++k) {
      float a[TM], bb[TN];
#pragma unroll
      for (int i = 0; i < TM; ++i) a[i] = As[k][tm * TM + i];
#pragma unroll
      for (int jj = 0; jj < TN; ++jj) bb[jj] = Bs[k][tn * TN + jj];
#pragma unroll
      for (int i = 0; i < TM; ++i)
#pragma unroll
        for (int jj = 0; jj < TN; ++jj) acc[i][jj] = fmaf(a[i], bb[jj], acc[i][jj]);
    }
    __syncthreads();
  }
#pragma unroll
  for (int i = 0; i < TM; ++i)
#pragma unroll
    for (int jj = 0; jj < TN; ++jj)
      C[(size_t)(m0 + tm * TM + i) * N + n0 + tn * TN + jj] = acc[i][jj];
}

// ---------------------------------------------------------------------------
// Per-group barrier (no fences; sc1 slot stores + polls)
// ---------------------------------------------------------------------------
__device__ __forceinline__ void group_barrier(int* slots, int grp, int j, int g) {
  asm volatile("s_waitcnt vmcnt(0)" ::: "memory");
  __syncthreads();
  if (threadIdx.x == 0) st_sci(&slots[(grp * GBLK + j) * SLOT_STRIDE], g);
  if (threadIdx.x < GBLK) {
    while (ld_sci(&slots[(grp * GBLK + (int)threadIdx.x) * SLOT_STRIDE]) < g)
      __builtin_amdgcn_s_sleep(1);
  }
  __syncthreads();
  asm volatile("" ::: "memory");
}

// ---------------------------------------------------------------------------
// Persistent decoder. Waves act as k-slices in P1/P2/P4 (cross-wave reduce in
// LDS); mutable cross-block traffic via wide sc0sc1; weights/ctx/ctxp cached.
// ---------------------------------------------------------------------------
__global__ __launch_bounds__(NTHR) void decoder_fused(
    const float* __restrict__ emb, const float* __restrict__ dec,
    const float* __restrict__ ctx, const float* __restrict__ Wi,
    const float* __restrict__ bi, const float* __restrict__ Wh,
    const float* __restrict__ bh, const float* __restrict__ Wha,
    const float* __restrict__ v, const float* __restrict__ Wout,
    const float* __restrict__ bout, const float* __restrict__ c0,
    const float* __restrict__ ctxp, float* __restrict__ g_hTc,
    float* __restrict__ g_hiTc, float* __restrict__ g_q,
    float* __restrict__ g_hp, float* __restrict__ g_att,
    int* __restrict__ g_sel, int* __restrict__ slots,
    float* __restrict__ out) {
  const int bid = blockIdx.x, tid = threadIdx.x;
  const int grp = bid >> 5, j = bid & 31;
  const int r0 = grp * GBLK, rb = bid;
  const int wv = tid >> 6, ln = tid & 63;
  const int rg = ln >> 3, cg = ln & 7;

  __shared__ float cslab[GBLK][17];
  __shared__ float maskS[S];
  __shared__ int selS[GBLK];
  __shared__ float red[4];
  __shared__ int redi[2];

  __shared__ union {
    struct {
      union {
        struct { float As[64][36]; float Bs[64][64]; } st;
        float prt[8][32][68];
      };
      float gT[64][33];
      float hiT[32][20];
    } p1;
    struct {
      union { float hiT[512][36]; float prt[8][32][36]; };
      float Bs2[512][32];
    } p2;
    struct { float qsS[512]; float es[S]; float attp[8][516]; } p3;
    struct {
      union { float attT[512][36]; float prt[8][32][20]; };
      float Bs4[512][16];
      float hpS[32][20];
      float hT[32][20];
    } p4;
  } sh;

  const float* g_hTc_g = g_hTc + (size_t)grp * 8 * 64 * 36;
  float* g_hiTc_g = g_hiTc + (size_t)grp * 512 * 36;

  // persistent state
  {
    int row = tid >> 4, u = tid & 15;
    cslab[row][u] = c0[(size_t)(r0 + row) * H + (j << 4) + u];
  }
  if (tid < S) maskS[tid] = 1.f;

  for (int t = 0; t < S; ++t) {
    const int gb = t * 4;

    // ===== P1: gates = [h|x]@[Wh;Wi]+biases -> cell -> h_i (block: 64 cols) ==
    {
      if (t > 0 && tid < GBLK) selS[tid] = ld_sci(&g_sel[r0 + tid]);
      __syncthreads();

      float acc[4][8];
#pragma unroll
      for (int i2 = 0; i2 < 4; ++i2)
#pragma unroll
        for (int j2 = 0; j2 < 8; ++j2) acc[i2][j2] = 0.f;

      const int bk0 = tid >> 4, bm = tid & 15;
      const int bq = bm >> 2, boff = (bm & 3) * 4;

      for (int part = 0; part < 2; ++part) {
        const float* Wp = part ? Wi : Wh;
        for (int ch = 0; ch < 8; ++ch) {
          const int kk = ch * 64;
          f4v w0c = *reinterpret_cast<const f4v*>(
              Wp + (size_t)(kk + bk0) * 2048 + bq * 512 + (j << 4) + boff);
          f4v w1c = *reinterpret_cast<const f4v*>(
              Wp + (size_t)(kk + 32 + bk0) * 2048 + bq * 512 + (j << 4) + boff);
          if (part == 0) {
            const float* src = g_hTc_g + (size_t)ch * 2304;
            f4v sv0, sv1;
            ld4cc(&sv0, src + tid * 4);
            const bool ex = tid < 64;
            if (ex) ld4cc(&sv1, src + (512 + tid) * 4);
            vmwait0();
            float* asf = &sh.p1.st.As[0][0];
            *reinterpret_cast<f4v*>(asf + tid * 4) = sv0;
            if (ex) *reinterpret_cast<f4v*>(asf + (512 + tid) * 4) = sv1;
          } else {
            const int srow = tid >> 4, m = tid & 15;
            const float* xr = (t == 0)
                ? dec + (size_t)(r0 + srow) * H
                : emb + ((size_t)(r0 + srow) * S + selS[srow]) * H;
            float4 xv = *reinterpret_cast<const float4*>(xr + kk + 4 * m);
            sh.p1.st.As[4 * m + 0][srow] = xv.x;
            sh.p1.st.As[4 * m + 1][srow] = xv.y;
            sh.p1.st.As[4 * m + 2][srow] = xv.z;
            sh.p1.st.As[4 * m + 3][srow] = xv.w;
          }
          *reinterpret_cast<f4v*>(&sh.p1.st.Bs[bk0][4 * bm]) = w0c;
          *reinterpret_cast<f4v*>(&sh.p1.st.Bs[32 + bk0][4 * bm]) = w1c;
          __syncthreads();
          const int kb = 8 * wv;
#pragma unroll
          for (int kx = 0; kx < 8; ++kx) {
            const int k = kb + kx;
            f4v a = *reinterpret_cast<const f4v*>(&sh.p1.st.As[k][4 * rg]);
            f4v b0 = *reinterpret_cast<const f4v*>(&sh.p1.st.Bs[k][4 * cg]);
            f4v b1 = *reinterpret_cast<const f4v*>(&sh.p1.st.Bs[k][32 + 4 * cg]);
#pragma unroll
            for (int i2 = 0; i2 < 4; ++i2) {
#pragma unroll
              for (int j2 = 0; j2 < 4; ++j2) {
                acc[i2][j2] = fmaf(a[i2], b0[j2], acc[i2][j2]);
                acc[i2][4 + j2] = fmaf(a[i2], b1[j2], acc[i2][4 + j2]);
              }
            }
          }
          __syncthreads();
        }
      }
#pragma unroll
      for (int i2 = 0; i2 < 4; ++i2) {
        f4v w0 = {acc[i2][0], acc[i2][1], acc[i2][2], acc[i2][3]};
        f4v w1 = {acc[i2][4], acc[i2][5], acc[i2][6], acc[i2][7]};
        *reinterpret_cast<f4v*>(&sh.p1.prt[wv][4 * rg + i2][4 * cg]) = w0;
        *reinterpret_cast<f4v*>(&sh.p1.prt[wv][4 * rg + i2][32 + 4 * cg]) = w1;
      }
      __syncthreads();
      {
        const int r = tid >> 4, c = 4 * (tid & 15);
        f4v s = *reinterpret_cast<const f4v*>(&sh.p1.prt[0][r][c]);
#pragma unroll
        for (int w = 1; w < 8; ++w) {
          f4v p = *reinterpret_cast<const f4v*>(&sh.p1.prt[w][r][c]);
          s[0] += p[0]; s[1] += p[1]; s[2] += p[2]; s[3] += p[3];
        }
#pragma unroll
        for (int e = 0; e < 4; ++e) {
          int vc = c + e;
          int gcol = ((vc >> 4) << 9) + (j << 4) + (vc & 15);
          sh.p1.gT[vc][r] = s[e] + bi[gcol] + bh[gcol];
        }
      }
      __syncthreads();
      // ---- LSTM cell (sigmoid on all 4 gates; fast transcendentals) ----
      {
        int row = tid >> 4, u = tid & 15;
        float gi = fast_sigm(sh.p1.gT[u][row]);
        float gf = fast_sigm(sh.p1.gT[u + 16][row]);
        float gg = fast_sigm(sh.p1.gT[u + 32][row]);
        float go = fast_sigm(sh.p1.gT[u + 48][row]);
        float cn = gf * cslab[row][u] + gi * gg;
        cslab[row][u] = cn;
        sh.p1.hiT[row][u] = go * fast_tanh(cn);
      }
      __syncthreads();
      if (tid < 128) {
        int u = tid >> 3, rw = tid & 7;
        f4v hv = {sh.p1.hiT[4 * rw + 0][u], sh.p1.hiT[4 * rw + 1][u],
                  sh.p1.hiT[4 * rw + 2][u], sh.p1.hiT[4 * rw + 3][u]};
        st4cc(&g_hiTc_g[((j << 4) + u) * 36 + 4 * rw], hv);
      }
    }
    group_barrier(slots, grp, j, gb + 1);

    // ===== P2: [q | hpart] = h_i @ [Wha | Wout2], 32-col slab ===============
    {
      {
        f4v bufs[9];
#pragma unroll
        for (int i2 = 0; i2 < 9; ++i2) {
          int lin = tid + i2 * 512;
          ld4cc(&bufs[i2], g_hiTc_g + lin * 4);
        }
        vmwait0();
        float* hf = &sh.p2.hiT[0][0];
#pragma unroll
        for (int i2 = 0; i2 < 9; ++i2) {
          int lin = tid + i2 * 512;
          *reinterpret_cast<f4v*>(hf + lin * 4) = bufs[i2];
        }
      }
      const float* Wp; int c0c;
      if (j < 16) { Wp = Wha; c0c = 32 * j; }
      else        { Wp = Wout + (size_t)H * H; c0c = 32 * j - 512; }
#pragma unroll
      for (int i2 = 0; i2 < 8; ++i2) {
        int lin = tid + i2 * 512;
        int k = lin >> 3, cq = (lin & 7) * 4;
        *reinterpret_cast<f4v*>(&sh.p2.Bs2[k][cq]) =
            *reinterpret_cast<const f4v*>(Wp + (size_t)k * 512 + c0c + cq);
      }
      __syncthreads();
      float qa[4][4];
#pragma unroll
      for (int i2 = 0; i2 < 4; ++i2)
#pragma unroll
        for (int j2 = 0; j2 < 4; ++j2) qa[i2][j2] = 0.f;
      const int kb = 64 * wv;
#pragma unroll 8
      for (int kx = 0; kx < 64; ++kx) {
        const int k = kb + kx;
        f4v a = *reinterpret_cast<const f4v*>(&sh.p2.hiT[k][4 * rg]);
        f4v b = *reinterpret_cast<const f4v*>(&sh.p2.Bs2[k][4 * cg]);
#pragma unroll
        for (int i2 = 0; i2 < 4; ++i2)
#pragma unroll
          for (int j2 = 0; j2 < 4; ++j2) qa[i2][j2] = fmaf(a[i2], b[j2], qa[i2][j2]);
      }
      __syncthreads();
#pragma unroll
      for (int i2 = 0; i2 < 4; ++i2) {
        f4v w0 = {qa[i2][0], qa[i2][1], qa[i2][2], qa[i2][3]};
        *reinterpret_cast<f4v*>(&sh.p2.prt[wv][4 * rg + i2][4 * cg]) = w0;
      }
      __syncthreads();
      if (tid < 256) {
        int r = tid >> 3, c4 = (tid & 7) * 4;
        f4v s = *reinterpret_cast<const f4v*>(&sh.p2.prt[0][r][c4]);
#pragma unroll
        for (int w = 1; w < 8; ++w) {
          f4v p = *reinterpret_cast<const f4v*>(&sh.p2.prt[w][r][c4]);
          s[0] += p[0]; s[1] += p[1]; s[2] += p[2]; s[3] += p[3];
        }
        float* Co = (j < 16) ? g_q : g_hp;
        st4cc(&Co[(size_t)(r0 + r) * H + c0c + c4], s);
      }
    }
    group_barrier(slots, grp, j, gb + 2);

    // ===== P3: scores+softmax+argmax+att for row rb (3-deep pipeline) =======
    {
      {
        f4v qv;
        const bool qld = tid < 128;
        if (qld) ld4cc(&qv, &g_q[(size_t)rb * H + tid * 4]);
        vmwait0();
        if (qld) *reinterpret_cast<f4v*>(&sh.p3.qsS[tid * 4]) = qv;
      }
      __syncthreads();
      const int col = ln * 8;
      float4 qv0 = *reinterpret_cast<const float4*>(&sh.p3.qsS[col]);
      float4 qv1 = *reinterpret_cast<const float4*>(&sh.p3.qsS[col + 4]);
      float4 vv0 = *reinterpret_cast<const float4*>(v + col);
      float4 vv1 = *reinterpret_cast<const float4*>(v + col + 4);
      float mk16 = maskS[(wv << 4) + (ln & 15)];
      uint32_t abits = (uint32_t)__ballot(mk16 != 0.f) & 0xFFFFu;
      if (ln < 16 && mk16 == 0.f) sh.p3.es[(wv << 4) + ln] = 0.f;

      float a0 = 0.f, a1 = 0.f, a2 = 0.f, a3 = 0.f;
      float a4 = 0.f, a5 = 0.f, a6 = 0.f, a7 = 0.f;
      const float* cpb = ctxp + ((size_t)rb * S + (wv << 4)) * H + col;
      const float* cxb = ctx + ((size_t)rb * S + (wv << 4)) * H + col;

      uint32_t bb = abits;
      auto pop = [&]() -> int {
        if (!bb) return -1;
        int r = (int)__builtin_ctz(bb);
        bb &= bb - 1;
        return r;
      };
      auto p3load = [&](float4& P0, float4& P1, float4& X0, float4& X1, int i) {
        P0 = *reinterpret_cast<const float4*>(cpb + (size_t)i * H);
        P1 = *reinterpret_cast<const float4*>(cpb + (size_t)i * H + 4);
        X0 = *reinterpret_cast<const float4*>(cxb + (size_t)i * H);
        X1 = *reinterpret_cast<const float4*>(cxb + (size_t)i * H + 4);
      };
      auto p3comp = [&](const float4& P0, const float4& P1, const float4& X0,
                        const float4& X1, int i) {
        float t0 = vv0.x * fast_tanh(P0.x + qv0.x);
        float t1 = vv0.y * fast_tanh(P0.y + qv0.y);
        float t2 = vv0.z * fast_tanh(P0.z + qv0.z);
        float t3 = vv0.w * fast_tanh(P0.w + qv0.w);
        float t4 = vv1.x * fast_tanh(P1.x + qv1.x);
        float t5 = vv1.y * fast_tanh(P1.y + qv1.y);
        float t6 = vv1.z * fast_tanh(P1.z + qv1.z);
        float t7 = vv1.w * fast_tanh(P1.w + qv1.w);
        float part = ((t0 + t1) + (t2 + t3)) + ((t4 + t5) + (t6 + t7));
        part = wave_sum64_hi(part);        // DPP tree (VALU), not ds_bpermute
        float sfull = bcast63(part);
        float e2 = fast_exp(sfull);        // uniform across lanes
        if (ln == 63) sh.p3.es[(wv << 4) + i] = e2;
        a0 = fmaf(e2, X0.x, a0);
        a1 = fmaf(e2, X0.y, a1);
        a2 = fmaf(e2, X0.z, a2);
        a3 = fmaf(e2, X0.w, a3);
        a4 = fmaf(e2, X1.x, a4);
        a5 = fmaf(e2, X1.y, a5);
        a6 = fmaf(e2, X1.z, a6);
        a7 = fmaf(e2, X1.w, a7);
      };

      float4 A0, A1, A2, A3, B0, B1, B2, B3, C0, C1, C2, C3;
      int ia = pop(), ib = pop(), ic = pop();
      if (ia >= 0) p3load(A0, A1, A2, A3, ia);
      if (ib >= 0) p3load(B0, B1, B2, B3, ib);
      if (ic >= 0) p3load(C0, C1, C2, C3, ic);
      while (ia >= 0) {
        p3comp(A0, A1, A2, A3, ia);
        ia = pop();
        if (ia >= 0) p3load(A0, A1, A2, A3, ia);
        if (ib < 0) break;
        p3comp(B0, B1, B2, B3, ib);
        ib = pop();
        if (ib >= 0) p3load(B0, B1, B2, B3, ib);
        if (ic < 0) break;
        p3comp(C0, C1, C2, C3, ic);
        ic = pop();
        if (ic >= 0) p3load(C0, C1, C2, C3, ic);
      }
      {
        f4v w0 = {a0, a1, a2, a3}, w1 = {a4, a5, a6, a7};
        *reinterpret_cast<f4v*>(&sh.p3.attp[wv][col]) = w0;
        *reinterpret_cast<f4v*>(&sh.p3.attp[wv][col + 4]) = w1;
      }
      __syncthreads();

      float e = (tid < S) ? sh.p3.es[tid] : 0.f;
      float wsum = e;
#pragma unroll
      for (int o = 1; o < 64; o <<= 1) wsum += __shfl_xor(wsum, o);
      if (tid < S && (tid & 63) == 0) red[tid >> 6] = wsum;
      __syncthreads();
      const float sum = red[0] + red[1];

      float a = e / sum;
      if (tid < 32) {
        f4v ev = *reinterpret_cast<const f4v*>(&sh.p3.es[tid * 4]);
        f4v av = {ev[0] / sum, ev[1] / sum, ev[2] / sum, ev[3] / sum};
        *reinterpret_cast<f4v*>(&out[((size_t)rb * S + t) * S + tid * 4]) = av;
      }

      float mv = (tid < S) ? a : -1.f;
      int mi = tid & (S - 1);
#pragma unroll
      for (int o = 1; o < 64; o <<= 1) {
        float ov = __shfl_xor(mv, o);
        int oi = __shfl_xor(mi, o);
        if (ov > mv || (ov == mv && oi < mi)) { mv = ov; mi = oi; }
      }
      if (tid < S && (tid & 63) == 0) {
        red[2 + (tid >> 6)] = mv;
        redi[tid >> 6] = mi;
      }
      __syncthreads();
      if (tid == 0) {
        float bv = red[2];
        int bI = redi[0];
        if (red[3] > bv || (red[3] == bv && redi[1] < bI)) {
          bv = red[3];
          bI = redi[1];
        }
        out[(size_t)B * S * S + (size_t)rb * S + t] = (float)bI;
        maskS[bI] = 0.f;
        st_sci(&g_sel[rb], bI);
      }

      float accA = 0.f;
#pragma unroll
      for (int w = 0; w < 8; ++w) accA += sh.p3.attp[w][tid];
      sh.p3.attp[0][tid] = accA / sum;
      __syncthreads();
      if (tid < 128) {
        f4v av = {sh.p3.attp[0][tid * 4], sh.p3.attp[0][tid * 4 + 1],
                  sh.p3.attp[0][tid * 4 + 2], sh.p3.attp[0][tid * 4 + 3]};
        st4cc(&g_att[(size_t)rb * H + tid * 4], av);
      }
    }
    group_barrier(slots, grp, j, gb + 3);

    // ===== P4: h = tanh(att@Wout1 + hpart + bout), 16-col slab ==============
    {
      {
        const int srow = tid >> 4, m = tid & 15;
        f4v ab[8];
#pragma unroll
        for (int i2 = 0; i2 < 8; ++i2)
          ld4cc(&ab[i2], &g_att[(size_t)(r0 + srow) * H + i2 * 64 + 4 * m]);
        f4v hpv;
        const bool hld = tid < 128;
        if (hld)
          ld4cc(&hpv, &g_hp[(size_t)(r0 + (tid >> 2)) * H + (j << 4) + (tid & 3) * 4]);
#pragma unroll
        for (int i2 = 0; i2 < 4; ++i2) {
          int lin = tid + i2 * 512;
          int k = lin >> 2, cq = (lin & 3) * 4;
          *reinterpret_cast<f4v*>(&sh.p4.Bs4[k][cq]) =
              *reinterpret_cast<const f4v*>(Wout + (size_t)k * 512 + (j << 4) + cq);
        }
        vmwait0();
#pragma unroll
        for (int i2 = 0; i2 < 8; ++i2) {
#pragma unroll
          for (int e = 0; e < 4; ++e)
            sh.p4.attT[i2 * 64 + 4 * m + e][srow] = ab[i2][e];
        }
        if (hld)
          *reinterpret_cast<f4v*>(&sh.p4.hpS[tid >> 2][(tid & 3) * 4]) = hpv;
      }
      __syncthreads();
      float pa[4][2];
#pragma unroll
      for (int i2 = 0; i2 < 4; ++i2) { pa[i2][0] = 0.f; pa[i2][1] = 0.f; }
      const int kb = 64 * wv;
#pragma unroll 8
      for (int kx = 0; kx < 64; ++kx) {
        const int k = kb + kx;
        f4v a = *reinterpret_cast<const f4v*>(&sh.p4.attT[k][4 * rg]);
        float2 b2 = *reinterpret_cast<const float2*>(&sh.p4.Bs4[k][2 * cg]);
#pragma unroll
        for (int i2 = 0; i2 < 4; ++i2) {
          pa[i2][0] = fmaf(a[i2], b2.x, pa[i2][0]);
          pa[i2][1] = fmaf(a[i2], b2.y, pa[i2][1]);
        }
      }
      __syncthreads();
#pragma unroll
      for (int i2 = 0; i2 < 4; ++i2)
        *reinterpret_cast<float2*>(&sh.p4.prt[wv][4 * rg + i2][2 * cg]) =
            make_float2(pa[i2][0], pa[i2][1]);
      __syncthreads();
      {
        int r = tid >> 4, cc = tid & 15;
        float s2 = sh.p4.prt[0][r][cc];
#pragma unroll
        for (int w = 1; w < 8; ++w) s2 += sh.p4.prt[w][r][cc];
        int gcol = (j << 4) + cc;
        sh.p4.hT[r][cc] = fast_tanh(s2 + sh.p4.hpS[r][cc] + bout[gcol]);
      }
      __syncthreads();
      if (tid < 128) {
        int u = tid >> 3, rw = tid & 7;
        f4v hv = {sh.p4.hT[4 * rw + 0][u], sh.p4.hT[4 * rw + 1][u],
                  sh.p4.hT[4 * rw + 2][u], sh.p4.hT[4 * rw + 3][u]};
        int kloc = (j << 4) + u;
        int ch = kloc >> 6, k = kloc & 63;
        st4cc(&g_hTc[(((size_t)grp * 8 + ch) * 64 + k) * 36 + 4 * rw], hv);
      }
    }
    group_barrier(slots, grp, j, gb + 4);
  }
}

}  // namespace

// ---------------------------------------------------------------------------
extern "C" void kernel_launch(void* const* d_in, const int* in_sizes, int n_in,
                              void* d_out, int out_size, void* d_ws, size_t ws_size,
                              hipStream_t stream) {
  const float* emb  = (const float*)d_in[0];
  const float* dec  = (const float*)d_in[1];
  const float* h0   = (const float*)d_in[2];
  const float* c0   = (const float*)d_in[3];
  const float* ctx  = (const float*)d_in[4];
  const float* Wi   = (const float*)d_in[5];
  const float* bi   = (const float*)d_in[6];
  const float* Wh   = (const float*)d_in[7];
  const float* bh   = (const float*)d_in[8];
  const float* Wctx = (const float*)d_in[9];
  const float* Wha  = (const float*)d_in[10];
  const float* v    = (const float*)d_in[11];
  const float* Wout = (const float*)d_in[12];
  const float* bout = (const float*)d_in[13];
  float* out = (float*)d_out;

  float* ws = (float*)d_ws;
  float* ctxp   = ws;                                  // B*S*H
  float* g_hTc  = ctxp + (size_t)B * S * H;            // 147456
  float* g_hiTc = g_hTc + (size_t)8 * 8 * 64 * 36;     // 147456
  float* g_q    = g_hiTc + (size_t)8 * 512 * 36;       // B*H
  float* g_hp   = g_q + (size_t)B * H;                 // B*H
  float* g_att  = g_hp + (size_t)B * H;                // B*H
  int*   g_sel  = (int*)(g_att + (size_t)B * H);       // B
  int*   slots  = g_sel + B;                           // NBLK*SLOT_STRIDE

  init_kernel<<<(B * H + 511) / 512, 512, 0, stream>>>(g_hTc, slots, h0);

  gemm_pre<128, 128, 8, 8, 16><<<dim3(H / 128, (B * S) / 128), 256, 0, stream>>>(
      ctx, Wctx, ctxp, B * S, H, H);

  decoder_fused<<<NBLK, NTHR, 0, stream>>>(
      emb, dec, ctx, Wi, bi, Wh, bh, Wha, v, Wout, bout, c0,
      ctxp, g_hTc, g_hiTc, g_q, g_hp, g_att, g_sel, slots, out);
}